// Round 1
// baseline (522.982 us; speedup 1.0000x reference)
//
#include <hip/hip_runtime.h>
#include <hip/hip_bf16.h>
#include <math.h>

#define V_ 50000
#define E_ 256
#define H_ 256
#define B_ 64
#define S_ 2048

#define TS 32      // s-rows per block in attn_scores
#define NCH 16     // context chunks
#define SC (S_ / NCH)

// ---------------- prep: xU = x@U ; xWih = x@W_ih^T + b_ih + b_hh ----------------
__global__ __launch_bounds__(256) void prep_k(
    const int* __restrict__ inp, const float* __restrict__ emb,
    const float* __restrict__ U, const float* __restrict__ W_ih,
    const float* __restrict__ b_ih, const float* __restrict__ b_hh,
    float* __restrict__ xU, float* __restrict__ xWih) {
  const int b = blockIdx.x, h = threadIdx.x;
  __shared__ float xs[H_];
  const float xv = emb[(size_t)inp[b] * E_ + h];
  xs[h] = xv;
  __syncthreads();
  float au = 0.f, aw = 0.f;
  const float* __restrict__ wir = W_ih + (size_t)h * E_;
  for (int k = 0; k < H_; k += 4) {
    const float4 x4 = *reinterpret_cast<const float4*>(&xs[k]);
    const float4 w4 = *reinterpret_cast<const float4*>(wir + k);
    aw = fmaf(x4.x, w4.x, aw); aw = fmaf(x4.y, w4.y, aw);
    aw = fmaf(x4.z, w4.z, aw); aw = fmaf(x4.w, w4.w, aw);
    au = fmaf(x4.x, U[(size_t)(k + 0) * H_ + h], au);
    au = fmaf(x4.y, U[(size_t)(k + 1) * H_ + h], au);
    au = fmaf(x4.z, U[(size_t)(k + 2) * H_ + h], au);
    au = fmaf(x4.w, U[(size_t)(k + 3) * H_ + h], au);
  }
  xU[b * H_ + h] = au;
  xWih[b * H_ + h] = aw + b_ih[h] + b_hh[h];
}

// ---------------- attention scores: e[b][s] = v . tanh(xU[b] + enc[b][s] @ W) ----------------
__global__ __launch_bounds__(256) void attn_scores(
    const float* __restrict__ enc, const float* __restrict__ Wg,
    const float* __restrict__ xU, const float* __restrict__ vv,
    float* __restrict__ e) {
  const int b = blockIdx.y;
  const int s0 = blockIdx.x * TS;
  const int h = threadIdx.x;
  const float* __restrict__ encB = enc + ((size_t)b * S_ + s0) * H_;  // wave-uniform base
  float acc[TS];
#pragma unroll
  for (int r = 0; r < TS; ++r) acc[r] = 0.f;
  for (int k = 0; k < H_; k += 4) {
    const float w0 = Wg[(size_t)(k + 0) * H_ + h];
    const float w1 = Wg[(size_t)(k + 1) * H_ + h];
    const float w2 = Wg[(size_t)(k + 2) * H_ + h];
    const float w3 = Wg[(size_t)(k + 3) * H_ + h];
#pragma unroll
    for (int r = 0; r < TS; ++r) {
      const float4 ev = *reinterpret_cast<const float4*>(encB + (size_t)r * H_ + k);
      acc[r] = fmaf(ev.x, w0, acc[r]);
      acc[r] = fmaf(ev.y, w1, acc[r]);
      acc[r] = fmaf(ev.z, w2, acc[r]);
      acc[r] = fmaf(ev.w, w3, acc[r]);
    }
  }
  const float xu = xU[b * H_ + h];
  const float vh = vv[h];
  __shared__ float red[4][TS];
  const int lane = h & 63, wv = h >> 6;
#pragma unroll
  for (int r = 0; r < TS; ++r) {
    float p = tanhf(xu + acc[r]) * vh;
    for (int o = 32; o; o >>= 1) p += __shfl_xor(p, o);
    if (lane == 0) red[wv][r] = p;
  }
  __syncthreads();
  if (h < TS) {
    e[(size_t)b * S_ + s0 + h] = red[0][h] + red[1][h] + red[2][h] + red[3][h];
  }
}

// ---------------- softmax over S (in place) ----------------
__global__ __launch_bounds__(256) void softmax_k(float* __restrict__ e) {
  const int b = blockIdx.x, t = threadIdx.x;
  float* row = e + (size_t)b * S_;
  float4 a = *reinterpret_cast<float4*>(row + t * 8);
  float4 c = *reinterpret_cast<float4*>(row + t * 8 + 4);
  float m = fmaxf(fmaxf(fmaxf(a.x, a.y), fmaxf(a.z, a.w)),
                  fmaxf(fmaxf(c.x, c.y), fmaxf(c.z, c.w)));
  __shared__ float lds[4];
  for (int o = 32; o; o >>= 1) m = fmaxf(m, __shfl_xor(m, o));
  if ((t & 63) == 0) lds[t >> 6] = m;
  __syncthreads();
  m = fmaxf(fmaxf(lds[0], lds[1]), fmaxf(lds[2], lds[3]));
  __syncthreads();
  a.x = expf(a.x - m); a.y = expf(a.y - m); a.z = expf(a.z - m); a.w = expf(a.w - m);
  c.x = expf(c.x - m); c.y = expf(c.y - m); c.z = expf(c.z - m); c.w = expf(c.w - m);
  float s = a.x + a.y + a.z + a.w + c.x + c.y + c.z + c.w;
  for (int o = 32; o; o >>= 1) s += __shfl_xor(s, o);
  if ((t & 63) == 0) lds[t >> 6] = s;
  __syncthreads();
  s = lds[0] + lds[1] + lds[2] + lds[3];
  const float inv = 1.0f / s;
  a.x *= inv; a.y *= inv; a.z *= inv; a.w *= inv;
  c.x *= inv; c.y *= inv; c.z *= inv; c.w *= inv;
  *reinterpret_cast<float4*>(row + t * 8) = a;
  *reinterpret_cast<float4*>(row + t * 8 + 4) = c;
}

// ---------------- context partials: part[c][b][h] = sum_{s in chunk} alpha[b][s]*enc[b][s][h] ----------------
__global__ __launch_bounds__(256) void ctx_partial(
    const float* __restrict__ enc, const float* __restrict__ alpha,
    float* __restrict__ part) {
  const int c = blockIdx.x, b = blockIdx.y, h = threadIdx.x;
  const float* __restrict__ eB = enc + ((size_t)b * S_ + c * SC) * H_ + h;
  const float* __restrict__ aB = alpha + (size_t)b * S_ + c * SC;  // wave-uniform
  float ps = 0.f;
#pragma unroll 4
  for (int s = 0; s < SC; ++s) ps = fmaf(aB[s], eB[(size_t)s * H_], ps);
  part[((size_t)c * B_ + b) * H_ + h] = ps;
}

// ---------------- reduce partials ----------------
__global__ __launch_bounds__(256) void ctx_reduce(
    const float* __restrict__ part, float* __restrict__ ctx) {
  const int i = blockIdx.x * 256 + threadIdx.x;  // (b,h)
  float s = 0.f;
#pragma unroll
  for (int c = 0; c < NCH; ++c) s += part[(size_t)c * B_ * H_ + i];
  ctx[i] = s;
}

// ---------------- h_new = tanh(xWih + ctx @ W_hh^T) ----------------
__global__ __launch_bounds__(256) void hnew_k(
    const float* __restrict__ ctx, const float* __restrict__ xWih,
    const float* __restrict__ W_hh, float* __restrict__ hnew,
    float* __restrict__ out_h) {
  const int b = blockIdx.x, h = threadIdx.x;
  __shared__ float cs[H_];
  cs[h] = ctx[b * H_ + h];
  __syncthreads();
  const float* __restrict__ wr = W_hh + (size_t)h * H_;
  float a = xWih[b * H_ + h];
  for (int k = 0; k < H_; k += 4) {
    const float4 w4 = *reinterpret_cast<const float4*>(wr + k);
    const float4 c4 = *reinterpret_cast<const float4*>(&cs[k]);
    a = fmaf(c4.x, w4.x, a); a = fmaf(c4.y, w4.y, a);
    a = fmaf(c4.z, w4.z, a); a = fmaf(c4.w, w4.w, a);
  }
  const float hv = tanhf(a);
  hnew[b * H_ + h] = hv;
  out_h[b * H_ + h] = hv;
}

// ---------------- logits = h_new @ W_out^T + b_out ----------------
__global__ __launch_bounds__(256) void logits_k(
    const float* __restrict__ Wout, const float* __restrict__ bout,
    const float* __restrict__ hn, float* __restrict__ logits) {
  const int lane = threadIdx.x & 63;
  const int wv = __builtin_amdgcn_readfirstlane(threadIdx.x >> 6);
  const int v = blockIdx.x * 64 + lane;
  const int vc = v < V_ ? v : V_ - 1;
  const float* __restrict__ wr = Wout + (size_t)vc * H_;
  const float* __restrict__ hb = hn + (size_t)wv * 16 * H_;  // wave-uniform
  float acc[16];
#pragma unroll
  for (int j = 0; j < 16; ++j) acc[j] = 0.f;
  for (int k = 0; k < H_; k += 4) {
    const float4 w4 = *reinterpret_cast<const float4*>(wr + k);
#pragma unroll
    for (int j = 0; j < 16; ++j) {
      const float4 h4 = *reinterpret_cast<const float4*>(hb + j * H_ + k);
      acc[j] = fmaf(w4.x, h4.x, acc[j]);
      acc[j] = fmaf(w4.y, h4.y, acc[j]);
      acc[j] = fmaf(w4.z, h4.z, acc[j]);
      acc[j] = fmaf(w4.w, h4.w, acc[j]);
    }
  }
  if (v < V_) {
    const float bo = bout[v];
#pragma unroll
    for (int j = 0; j < 16; ++j)
      logits[(size_t)(wv * 16 + j) * V_ + v] = acc[j] + bo;
  }
}

extern "C" void kernel_launch(void* const* d_in, const int* in_sizes, int n_in,
                              void* d_out, int out_size, void* d_ws, size_t ws_size,
                              hipStream_t stream) {
  const int*   inp  = (const int*)  d_in[0];
  // d_in[1] = hidden (unused by reference)
  const float* enc  = (const float*)d_in[2];
  const float* emb  = (const float*)d_in[3];
  const float* U    = (const float*)d_in[4];
  const float* W    = (const float*)d_in[5];
  const float* v    = (const float*)d_in[6];
  const float* W_ih = (const float*)d_in[7];
  const float* W_hh = (const float*)d_in[8];
  const float* b_ih = (const float*)d_in[9];
  const float* b_hh = (const float*)d_in[10];
  const float* Wout = (const float*)d_in[11];
  const float* bout = (const float*)d_in[12];

  float* logits = (float*)d_out;
  float* out_h  = logits + (size_t)B_ * V_;

  float* ws   = (float*)d_ws;
  float* xU   = ws;                       // B*H
  float* xWih = xU + B_ * H_;             // B*H
  float* e    = xWih + B_ * H_;           // B*S
  float* part = e + (size_t)B_ * S_;      // NCH*B*H
  float* ctx  = part + (size_t)NCH * B_ * H_;  // B*H
  float* hnew = ctx + B_ * H_;            // B*H

  prep_k<<<dim3(B_), dim3(256), 0, stream>>>(inp, emb, U, W_ih, b_ih, b_hh, xU, xWih);
  attn_scores<<<dim3(S_ / TS, B_), dim3(256), 0, stream>>>(enc, W, xU, v, e);
  softmax_k<<<dim3(B_), dim3(256), 0, stream>>>(e);
  ctx_partial<<<dim3(NCH, B_), dim3(256), 0, stream>>>(enc, e, part);
  ctx_reduce<<<dim3(B_ * H_ / 256), dim3(256), 0, stream>>>(part, ctx);
  hnew_k<<<dim3(B_), dim3(256), 0, stream>>>(ctx, xWih, W_hh, hnew, out_h);
  logits_k<<<dim3((V_ + 63) / 64), dim3(256), 0, stream>>>(Wout, bout, hnew, logits);
}

// Round 2
// 201.470 us; speedup vs baseline: 2.5958x; 2.5958x over previous
//
#include <hip/hip_runtime.h>
#include <hip/hip_bf16.h>
#include <math.h>

#define V_ 50000
#define E_ 256
#define H_ 256
#define B_ 64
#define S_ 2048

#define NCH 16     // context chunks
#define SC (S_ / NCH)

typedef __attribute__((ext_vector_type(4))) float f32x4;
typedef __attribute__((ext_vector_type(8))) __bf16 bf16x8;

static __device__ __forceinline__ f32x4 mfma16(bf16x8 a, bf16x8 b, f32x4 c) {
  return __builtin_amdgcn_mfma_f32_16x16x32_bf16(a, b, c, 0, 0, 0);
}

// ---------------- prep: xU = x@U ; xWih = x@W_ih^T + b_ih + b_hh ----------------
__global__ __launch_bounds__(256) void prep_k(
    const int* __restrict__ inp, const float* __restrict__ emb,
    const float* __restrict__ U, const float* __restrict__ W_ih,
    const float* __restrict__ b_ih, const float* __restrict__ b_hh,
    float* __restrict__ xU, float* __restrict__ xWih) {
  const int b = blockIdx.x, h = threadIdx.x;
  __shared__ float xs[H_];
  const float xv = emb[(size_t)inp[b] * E_ + h];
  xs[h] = xv;
  __syncthreads();
  float au = 0.f, aw = 0.f;
  const float* __restrict__ wir = W_ih + (size_t)h * E_;
  for (int k = 0; k < H_; k += 4) {
    const float4 x4 = *reinterpret_cast<const float4*>(&xs[k]);
    const float4 w4 = *reinterpret_cast<const float4*>(wir + k);
    aw = fmaf(x4.x, w4.x, aw); aw = fmaf(x4.y, w4.y, aw);
    aw = fmaf(x4.z, w4.z, aw); aw = fmaf(x4.w, w4.w, aw);
    au = fmaf(x4.x, U[(size_t)(k + 0) * H_ + h], au);
    au = fmaf(x4.y, U[(size_t)(k + 1) * H_ + h], au);
    au = fmaf(x4.z, U[(size_t)(k + 2) * H_ + h], au);
    au = fmaf(x4.w, U[(size_t)(k + 3) * H_ + h], au);
  }
  xU[b * H_ + h] = au;
  xWih[b * H_ + h] = aw + b_ih[h] + b_hh[h];
}

// ---------------- prep W: transposed hi/lo bf16 tables Wt[n][k] ----------------
__global__ __launch_bounds__(256) void prep_w(
    const float* __restrict__ W, __bf16* __restrict__ wt_hi, __bf16* __restrict__ wt_lo) {
  const int idx = blockIdx.x * 256 + threadIdx.x;
  const int n = idx >> 8, k = idx & 255;
  const float w = W[(size_t)k * H_ + n];
  const __bf16 h = (__bf16)w;
  const __bf16 l = (__bf16)(w - (float)h);
  wt_hi[(size_t)n * H_ + k] = h;
  wt_lo[(size_t)n * H_ + k] = l;
}

// ---------------- attention scores via MFMA ----------------
__global__ __launch_bounds__(256) void attn_mfma(
    const float* __restrict__ enc, const __bf16* __restrict__ wt_hi,
    const __bf16* __restrict__ wt_lo, const float* __restrict__ xU,
    const float* __restrict__ vv, float* __restrict__ e) {
  const int b = blockIdx.y;
  const int s0 = blockIdx.x * 64;
  const int t = threadIdx.x;
  const int lane = t & 63;
  const int wv = t >> 6;
  const int l15 = lane & 15;
  const int lg = lane >> 4;

  __shared__ __bf16 Ah[64 * 32];
  __shared__ __bf16 Al[64 * 32];
  __shared__ float ered[4][64];

  const int arow = t >> 2;
  const int achunk = t & 3;
  const int aslot = (achunk + (arow >> 1)) & 3;
  const float* __restrict__ encB = enc + ((size_t)b * S_ + s0) * H_;

  f32x4 acc[4][4];
#pragma unroll
  for (int i = 0; i < 4; ++i)
#pragma unroll
    for (int j = 0; j < 4; ++j) acc[i][j] = (f32x4)(0.f);

  for (int k0 = 0; k0 < H_; k0 += 32) {
    const float* gp = encB + (size_t)arow * H_ + k0 + achunk * 8;
    const float4 f0 = *reinterpret_cast<const float4*>(gp);
    const float4 f1 = *reinterpret_cast<const float4*>(gp + 4);
    __syncthreads();
    {
      float xv[8] = {f0.x, f0.y, f0.z, f0.w, f1.x, f1.y, f1.z, f1.w};
      bf16x8 h8, l8;
#pragma unroll
      for (int j = 0; j < 8; ++j) {
        const __bf16 h = (__bf16)xv[j];
        h8[j] = h;
        l8[j] = (__bf16)(xv[j] - (float)h);
      }
      *reinterpret_cast<bf16x8*>(&Ah[arow * 32 + aslot * 8]) = h8;
      *reinterpret_cast<bf16x8*>(&Al[arow * 32 + aslot * 8]) = l8;
    }
    __syncthreads();

    bf16x8 bh[4], bl[4];
    const __bf16* bp = wt_hi + (size_t)(wv * 64 + l15) * H_ + k0 + lg * 8;
    const __bf16* lp = wt_lo + (size_t)(wv * 64 + l15) * H_ + k0 + lg * 8;
#pragma unroll
    for (int cf = 0; cf < 4; ++cf) {
      bh[cf] = *reinterpret_cast<const bf16x8*>(bp + (size_t)cf * 16 * H_);
      bl[cf] = *reinterpret_cast<const bf16x8*>(lp + (size_t)cf * 16 * H_);
    }
    bf16x8 ah[4], al[4];
#pragma unroll
    for (int rf = 0; rf < 4; ++rf) {
      const int r = rf * 16 + l15;
      const int slot = (lg + (r >> 1)) & 3;
      ah[rf] = *reinterpret_cast<const bf16x8*>(&Ah[r * 32 + slot * 8]);
      al[rf] = *reinterpret_cast<const bf16x8*>(&Al[r * 32 + slot * 8]);
    }
#pragma unroll
    for (int rf = 0; rf < 4; ++rf)
#pragma unroll
      for (int cf = 0; cf < 4; ++cf) {
        acc[rf][cf] = mfma16(ah[rf], bh[cf], acc[rf][cf]);
        acc[rf][cf] = mfma16(al[rf], bh[cf], acc[rf][cf]);
        acc[rf][cf] = mfma16(ah[rf], bl[cf], acc[rf][cf]);
      }
  }

  float xu4[4], vv4[4];
#pragma unroll
  for (int cf = 0; cf < 4; ++cf) {
    const int col = wv * 64 + cf * 16 + l15;
    xu4[cf] = xU[b * H_ + col];
    vv4[cf] = vv[col];
  }
  float part[4][4];
#pragma unroll
  for (int rf = 0; rf < 4; ++rf)
#pragma unroll
    for (int reg = 0; reg < 4; ++reg) part[rf][reg] = 0.f;
#pragma unroll
  for (int rf = 0; rf < 4; ++rf)
#pragma unroll
    for (int cf = 0; cf < 4; ++cf) {
      const float xu = xu4[cf], vw = vv4[cf];
#pragma unroll
      for (int reg = 0; reg < 4; ++reg)
        part[rf][reg] += tanhf(xu + acc[rf][cf][reg]) * vw;
    }
#pragma unroll
  for (int o = 1; o < 16; o <<= 1)
#pragma unroll
    for (int rf = 0; rf < 4; ++rf)
#pragma unroll
      for (int reg = 0; reg < 4; ++reg)
        part[rf][reg] += __shfl_xor(part[rf][reg], o);
  if (l15 == 0) {
#pragma unroll
    for (int rf = 0; rf < 4; ++rf)
#pragma unroll
      for (int reg = 0; reg < 4; ++reg)
        ered[wv][rf * 16 + lg * 4 + reg] = part[rf][reg];
  }
  __syncthreads();
  if (t < 64)
    e[(size_t)b * S_ + s0 + t] = ered[0][t] + ered[1][t] + ered[2][t] + ered[3][t];
}

// ---------------- softmax over S (in place) ----------------
__global__ __launch_bounds__(256) void softmax_k(float* __restrict__ e) {
  const int b = blockIdx.x, t = threadIdx.x;
  float* row = e + (size_t)b * S_;
  float4 a = *reinterpret_cast<float4*>(row + t * 8);
  float4 c = *reinterpret_cast<float4*>(row + t * 8 + 4);
  float m = fmaxf(fmaxf(fmaxf(a.x, a.y), fmaxf(a.z, a.w)),
                  fmaxf(fmaxf(c.x, c.y), fmaxf(c.z, c.w)));
  __shared__ float lds[4];
  for (int o = 32; o; o >>= 1) m = fmaxf(m, __shfl_xor(m, o));
  if ((t & 63) == 0) lds[t >> 6] = m;
  __syncthreads();
  m = fmaxf(fmaxf(lds[0], lds[1]), fmaxf(lds[2], lds[3]));
  __syncthreads();
  a.x = expf(a.x - m); a.y = expf(a.y - m); a.z = expf(a.z - m); a.w = expf(a.w - m);
  c.x = expf(c.x - m); c.y = expf(c.y - m); c.z = expf(c.z - m); c.w = expf(c.w - m);
  float s = a.x + a.y + a.z + a.w + c.x + c.y + c.z + c.w;
  for (int o = 32; o; o >>= 1) s += __shfl_xor(s, o);
  if ((t & 63) == 0) lds[t >> 6] = s;
  __syncthreads();
  s = lds[0] + lds[1] + lds[2] + lds[3];
  const float inv = 1.0f / s;
  a.x *= inv; a.y *= inv; a.z *= inv; a.w *= inv;
  c.x *= inv; c.y *= inv; c.z *= inv; c.w *= inv;
  *reinterpret_cast<float4*>(row + t * 8) = a;
  *reinterpret_cast<float4*>(row + t * 8 + 4) = c;
}

// ---------------- context partials ----------------
__global__ __launch_bounds__(256) void ctx_partial(
    const float* __restrict__ enc, const float* __restrict__ alpha,
    float* __restrict__ part) {
  const int c = blockIdx.x, b = blockIdx.y, h = threadIdx.x;
  const float* __restrict__ eB = enc + ((size_t)b * S_ + c * SC) * H_ + h;
  const float* __restrict__ aB = alpha + (size_t)b * S_ + c * SC;
  float ps = 0.f;
#pragma unroll 4
  for (int s = 0; s < SC; ++s) ps = fmaf(aB[s], eB[(size_t)s * H_], ps);
  part[((size_t)c * B_ + b) * H_ + h] = ps;
}

__global__ __launch_bounds__(256) void ctx_reduce(
    const float* __restrict__ part, float* __restrict__ ctx) {
  const int i = blockIdx.x * 256 + threadIdx.x;
  float s = 0.f;
#pragma unroll
  for (int c = 0; c < NCH; ++c) s += part[(size_t)c * B_ * H_ + i];
  ctx[i] = s;
}

// ---------------- h_new = tanh(xWih + ctx @ W_hh^T) ----------------
__global__ __launch_bounds__(256) void hnew_k(
    const float* __restrict__ ctx, const float* __restrict__ xWih,
    const float* __restrict__ W_hh, float* __restrict__ hnew,
    float* __restrict__ out_h) {
  const int b = blockIdx.x, h = threadIdx.x;
  __shared__ float cs[H_];
  cs[h] = ctx[b * H_ + h];
  __syncthreads();
  const float* __restrict__ wr = W_hh + (size_t)h * H_;
  float a = xWih[b * H_ + h];
  for (int k = 0; k < H_; k += 4) {
    const float4 w4 = *reinterpret_cast<const float4*>(wr + k);
    const float4 c4 = *reinterpret_cast<const float4*>(&cs[k]);
    a = fmaf(c4.x, w4.x, a); a = fmaf(c4.y, w4.y, a);
    a = fmaf(c4.z, w4.z, a); a = fmaf(c4.w, w4.w, a);
  }
  const float hv = tanhf(a);
  hnew[b * H_ + h] = hv;
  out_h[b * H_ + h] = hv;
}

// ---------------- logits = h_new @ W_out^T + b_out ----------------
__global__ __launch_bounds__(256) void logits_k(
    const float* __restrict__ Wout, const float* __restrict__ bout,
    const float* __restrict__ hn, float* __restrict__ logits) {
  const int lane = threadIdx.x & 63;
  const int wv = __builtin_amdgcn_readfirstlane(threadIdx.x >> 6);
  const int v = blockIdx.x * 64 + lane;
  const int vc = v < V_ ? v : V_ - 1;
  const float* __restrict__ wr = Wout + (size_t)vc * H_;
  const float* __restrict__ hb = hn + (size_t)wv * 16 * H_;
  float acc[16];
#pragma unroll
  for (int j = 0; j < 16; ++j) acc[j] = 0.f;
  for (int k = 0; k < H_; k += 4) {
    const float4 w4 = *reinterpret_cast<const float4*>(wr + k);
#pragma unroll
    for (int j = 0; j < 16; ++j) {
      const float4 h4 = *reinterpret_cast<const float4*>(hb + j * H_ + k);
      acc[j] = fmaf(w4.x, h4.x, acc[j]);
      acc[j] = fmaf(w4.y, h4.y, acc[j]);
      acc[j] = fmaf(w4.z, h4.z, acc[j]);
      acc[j] = fmaf(w4.w, h4.w, acc[j]);
    }
  }
  if (v < V_) {
    const float bo = bout[v];
#pragma unroll
    for (int j = 0; j < 16; ++j)
      logits[(size_t)(wv * 16 + j) * V_ + v] = acc[j] + bo;
  }
}

extern "C" void kernel_launch(void* const* d_in, const int* in_sizes, int n_in,
                              void* d_out, int out_size, void* d_ws, size_t ws_size,
                              hipStream_t stream) {
  const int*   inp  = (const int*)  d_in[0];
  const float* enc  = (const float*)d_in[2];
  const float* emb  = (const float*)d_in[3];
  const float* U    = (const float*)d_in[4];
  const float* W    = (const float*)d_in[5];
  const float* v    = (const float*)d_in[6];
  const float* W_ih = (const float*)d_in[7];
  const float* W_hh = (const float*)d_in[8];
  const float* b_ih = (const float*)d_in[9];
  const float* b_hh = (const float*)d_in[10];
  const float* Wout = (const float*)d_in[11];
  const float* bout = (const float*)d_in[12];

  float* logits = (float*)d_out;
  float* out_h  = logits + (size_t)B_ * V_;

  float* ws     = (float*)d_ws;
  __bf16* wt_hi = (__bf16*)ws;                 // H*H bf16
  __bf16* wt_lo = wt_hi + (size_t)H_ * H_;     // H*H bf16
  float* xU   = ws + 65536;                    // after 256KB
  float* xWih = xU + B_ * H_;
  float* e    = xWih + B_ * H_;                // B*S
  float* part = e + (size_t)B_ * S_;           // NCH*B*H
  float* ctx  = part + (size_t)NCH * B_ * H_;
  float* hnew = ctx + B_ * H_;

  prep_k<<<dim3(B_), dim3(256), 0, stream>>>(inp, emb, U, W_ih, b_ih, b_hh, xU, xWih);
  prep_w<<<dim3(H_ * H_ / 256), dim3(256), 0, stream>>>(W, wt_hi, wt_lo);
  attn_mfma<<<dim3(S_ / 64, B_), dim3(256), 0, stream>>>(enc, wt_hi, wt_lo, xU, v, e);
  softmax_k<<<dim3(B_), dim3(256), 0, stream>>>(e);
  ctx_partial<<<dim3(NCH, B_), dim3(256), 0, stream>>>(enc, e, part);
  ctx_reduce<<<dim3(B_ * H_ / 256), dim3(256), 0, stream>>>(part, ctx);
  hnew_k<<<dim3(B_), dim3(256), 0, stream>>>(ctx, xWih, W_hh, hnew, out_h);
  logits_k<<<dim3((V_ + 63) / 64), dim3(256), 0, stream>>>(Wout, bout, hnew, logits);
}

// Round 3
// 157.244 us; speedup vs baseline: 3.3259x; 1.2813x over previous
//
#include <hip/hip_runtime.h>
#include <hip/hip_bf16.h>
#include <math.h>

#define V_ 50000
#define E_ 256
#define H_ 256
#define B_ 64
#define S_ 2048
#define NCH 16
#define SC (S_ / NCH)

typedef __attribute__((ext_vector_type(4))) float f32x4;
typedef __attribute__((ext_vector_type(8))) __bf16 bf16x8;

static __device__ __forceinline__ f32x4 mfma16(bf16x8 a, bf16x8 b, f32x4 c) {
  return __builtin_amdgcn_mfma_f32_16x16x32_bf16(a, b, c, 0, 0, 0);
}
// tanh(x) = 1 - 2/(exp(2x)+1); __expf -> v_exp_f32, branchless, inf-safe.
static __device__ __forceinline__ float fast_tanh(float x) {
  const float e2 = __expf(2.0f * x);
  return 1.0f - 2.0f / (e2 + 1.0f);
}

// ---------------- prep: xU = x@U ; xWih = x@W_ih^T + b_ih + b_hh ----------------
__global__ __launch_bounds__(256) void prep_k(
    const int* __restrict__ inp, const float* __restrict__ emb,
    const float* __restrict__ U, const float* __restrict__ W_ih,
    const float* __restrict__ b_ih, const float* __restrict__ b_hh,
    float* __restrict__ xU, float* __restrict__ xWih) {
  const int b = blockIdx.x, h = threadIdx.x;
  __shared__ float xs[H_];
  xs[h] = emb[(size_t)inp[b] * E_ + h];
  __syncthreads();
  float au = 0.f, aw = 0.f;
  const float* __restrict__ wir = W_ih + (size_t)h * E_;
  for (int k = 0; k < H_; k += 4) {
    const float4 x4 = *reinterpret_cast<const float4*>(&xs[k]);
    const float4 w4 = *reinterpret_cast<const float4*>(wir + k);
    aw = fmaf(x4.x, w4.x, aw); aw = fmaf(x4.y, w4.y, aw);
    aw = fmaf(x4.z, w4.z, aw); aw = fmaf(x4.w, w4.w, aw);
    au = fmaf(x4.x, U[(size_t)(k + 0) * H_ + h], au);
    au = fmaf(x4.y, U[(size_t)(k + 1) * H_ + h], au);
    au = fmaf(x4.z, U[(size_t)(k + 2) * H_ + h], au);
    au = fmaf(x4.w, U[(size_t)(k + 3) * H_ + h], au);
  }
  xU[b * H_ + h] = au;
  xWih[b * H_ + h] = aw + b_ih[h] + b_hh[h];
}

// ---------------- prep W: transposed hi/lo bf16 tables Wt[n][k] ----------------
__global__ __launch_bounds__(256) void prep_w(
    const float* __restrict__ W, __bf16* __restrict__ wt_hi, __bf16* __restrict__ wt_lo) {
  const int idx = blockIdx.x * 256 + threadIdx.x;
  const int n = idx >> 8, k = idx & 255;
  const float w = W[(size_t)k * H_ + n];
  const __bf16 h = (__bf16)w;
  wt_hi[(size_t)n * H_ + k] = h;
  wt_lo[(size_t)n * H_ + k] = (__bf16)(w - (float)h);
}

// ---------------- attention scores via MFMA, barrier-free K-loop ----------------
// block: 512 thr (8 waves); 64 s-rows x 256 cols. Full 64x256 tile staged once.
__global__ __launch_bounds__(512, 4) void attn_mfma(
    const float* __restrict__ enc, const __bf16* __restrict__ wt_hi,
    const __bf16* __restrict__ wt_lo, const float* __restrict__ xU,
    const float* __restrict__ vv, float* __restrict__ e) {
  const int b = blockIdx.y;
  const int s0 = blockIdx.x * 64;
  const int t = threadIdx.x;
  const int wv = t >> 6;
  const int l = t & 63;
  const int l15 = l & 15;
  const int lg = l >> 4;

  __shared__ __bf16 Ah[8 * 2048];   // 8 sub-tiles [64][32], slot-rotated
  __shared__ __bf16 Al[8 * 2048];
  __shared__ float ered[8][64];

  const float* __restrict__ encB = enc + ((size_t)b * S_ + s0) * H_;
  // stage sub-tile wv: k-cols [wv*32, wv*32+32), all 64 rows
  {
    const int chunk = l & 3;
#pragma unroll
    for (int i = 0; i < 4; ++i) {
      const int row = i * 16 + (l >> 2);
      const float* gp = encB + (size_t)row * H_ + wv * 32 + chunk * 8;
      const float4 f0 = *reinterpret_cast<const float4*>(gp);
      const float4 f1 = *reinterpret_cast<const float4*>(gp + 4);
      const int slot = (chunk + (row >> 1)) & 3;
      float xv[8] = {f0.x, f0.y, f0.z, f0.w, f1.x, f1.y, f1.z, f1.w};
      bf16x8 h8, l8;
#pragma unroll
      for (int j = 0; j < 8; ++j) {
        const __bf16 hh = (__bf16)xv[j];
        h8[j] = hh;
        l8[j] = (__bf16)(xv[j] - (float)hh);
      }
      *reinterpret_cast<bf16x8*>(&Ah[wv * 2048 + row * 32 + slot * 8]) = h8;
      *reinterpret_cast<bf16x8*>(&Al[wv * 2048 + row * 32 + slot * 8]) = l8;
    }
  }
  __syncthreads();

  f32x4 acc[4][2];
#pragma unroll
  for (int i = 0; i < 4; ++i)
#pragma unroll
    for (int j = 0; j < 2; ++j) acc[i][j] = (f32x4)(0.f);

  const int colb = wv * 32;
#pragma unroll
  for (int k0 = 0; k0 < H_; k0 += 32) {
    const int sub = k0 >> 5;
    bf16x8 bh[2], bl[2], ah[4], al[4];
#pragma unroll
    for (int cf = 0; cf < 2; ++cf) {
      const int col = colb + cf * 16 + l15;
      bh[cf] = *reinterpret_cast<const bf16x8*>(wt_hi + (size_t)col * H_ + k0 + lg * 8);
      bl[cf] = *reinterpret_cast<const bf16x8*>(wt_lo + (size_t)col * H_ + k0 + lg * 8);
    }
#pragma unroll
    for (int rf = 0; rf < 4; ++rf) {
      const int r = rf * 16 + l15;
      const int slot = (lg + (r >> 1)) & 3;
      ah[rf] = *reinterpret_cast<const bf16x8*>(&Ah[sub * 2048 + r * 32 + slot * 8]);
      al[rf] = *reinterpret_cast<const bf16x8*>(&Al[sub * 2048 + r * 32 + slot * 8]);
    }
#pragma unroll
    for (int rf = 0; rf < 4; ++rf)
#pragma unroll
      for (int cf = 0; cf < 2; ++cf) {
        acc[rf][cf] = mfma16(ah[rf], bh[cf], acc[rf][cf]);
        acc[rf][cf] = mfma16(al[rf], bh[cf], acc[rf][cf]);
        acc[rf][cf] = mfma16(ah[rf], bl[cf], acc[rf][cf]);
      }
  }

  float part[4][4];
#pragma unroll
  for (int rf = 0; rf < 4; ++rf)
#pragma unroll
    for (int reg = 0; reg < 4; ++reg) part[rf][reg] = 0.f;
#pragma unroll
  for (int cf = 0; cf < 2; ++cf) {
    const int col = colb + cf * 16 + l15;
    const float xu = xU[b * H_ + col];
    const float vw = vv[col];
#pragma unroll
    for (int rf = 0; rf < 4; ++rf)
#pragma unroll
      for (int reg = 0; reg < 4; ++reg)
        part[rf][reg] += fast_tanh(xu + acc[rf][cf][reg]) * vw;
  }
#pragma unroll
  for (int o = 1; o < 16; o <<= 1)
#pragma unroll
    for (int rf = 0; rf < 4; ++rf)
#pragma unroll
      for (int reg = 0; reg < 4; ++reg)
        part[rf][reg] += __shfl_xor(part[rf][reg], o);
  if (l15 == 0) {
#pragma unroll
    for (int rf = 0; rf < 4; ++rf)
#pragma unroll
      for (int reg = 0; reg < 4; ++reg)
        ered[wv][rf * 16 + lg * 4 + reg] = part[rf][reg];
  }
  __syncthreads();
  if (t < 64) {
    float s = 0.f;
#pragma unroll
    for (int w = 0; w < 8; ++w) s += ered[w][t];
    e[(size_t)b * S_ + s0 + t] = s;
  }
}

// ---------------- fused softmax + context partials ----------------
// block (c,b): recompute row softmax stats from e (L2-hot, 8KB), then chunk dot.
__global__ __launch_bounds__(256) void ctx_partial(
    const float* __restrict__ enc, const float* __restrict__ e,
    float* __restrict__ part) {
  const int c = blockIdx.x, b = blockIdx.y, t = threadIdx.x;
  const float* __restrict__ row = e + (size_t)b * S_;
  const float4 a = *reinterpret_cast<const float4*>(row + t * 8);
  const float4 d = *reinterpret_cast<const float4*>(row + t * 8 + 4);
  float m = fmaxf(fmaxf(fmaxf(a.x, a.y), fmaxf(a.z, a.w)),
                  fmaxf(fmaxf(d.x, d.y), fmaxf(d.z, d.w)));
  __shared__ float red[4];
  __shared__ float al_s[SC];
  for (int o = 32; o; o >>= 1) m = fmaxf(m, __shfl_xor(m, o));
  if ((t & 63) == 0) red[t >> 6] = m;
  __syncthreads();
  m = fmaxf(fmaxf(red[0], red[1]), fmaxf(red[2], red[3]));
  float s = __expf(a.x - m) + __expf(a.y - m) + __expf(a.z - m) + __expf(a.w - m) +
            __expf(d.x - m) + __expf(d.y - m) + __expf(d.z - m) + __expf(d.w - m);
  for (int o = 32; o; o >>= 1) s += __shfl_xor(s, o);
  __syncthreads();
  if ((t & 63) == 0) red[t >> 6] = s;
  __syncthreads();
  s = red[0] + red[1] + red[2] + red[3];
  const float inv = 1.0f / s;
  if (t < SC) al_s[t] = __expf(row[c * SC + t] - m) * inv;
  __syncthreads();
  const float* __restrict__ eB = enc + ((size_t)b * S_ + c * SC) * H_ + t;
  float ps = 0.f;
#pragma unroll 4
  for (int s2 = 0; s2 < SC; ++s2) ps = fmaf(al_s[s2], eB[(size_t)s2 * H_], ps);
  part[((size_t)c * B_ + b) * H_ + t] = ps;
}

// ---------------- h_new = tanh(xWih + ctx @ W_hh^T); fused ctx reduce; bf16 split out ----------------
__global__ __launch_bounds__(256) void hnew_k(
    const float* __restrict__ part, const float* __restrict__ xWih,
    const float* __restrict__ W_hh, float* __restrict__ out_h,
    __bf16* __restrict__ hn_hi, __bf16* __restrict__ hn_lo) {
  const int b = blockIdx.x, h = threadIdx.x;
  __shared__ float cs[H_];
  float ctxh = 0.f;
#pragma unroll
  for (int c = 0; c < NCH; ++c) ctxh += part[((size_t)c * B_ + b) * H_ + h];
  cs[h] = ctxh;
  __syncthreads();
  const float* __restrict__ wr = W_hh + (size_t)h * H_;
  float a = xWih[b * H_ + h];
  for (int k = 0; k < H_; k += 4) {
    const float4 w4 = *reinterpret_cast<const float4*>(wr + k);
    const float4 c4 = *reinterpret_cast<const float4*>(&cs[k]);
    a = fmaf(c4.x, w4.x, a); a = fmaf(c4.y, w4.y, a);
    a = fmaf(c4.z, w4.z, a); a = fmaf(c4.w, w4.w, a);
  }
  const float hv = fast_tanh(a);
  out_h[b * H_ + h] = hv;
  const __bf16 hh = (__bf16)hv;
  hn_hi[b * H_ + h] = hh;
  hn_lo[b * H_ + h] = (__bf16)(hv - (float)hh);
}

// ---------------- logits = h_new @ W_out^T + b_out via MFMA ----------------
// block: 256 thr (4 waves); 64 vocab rows x 64 batch cols; Wout tile staged hi/lo.
__global__ __launch_bounds__(256, 4) void logits_mfma(
    const float* __restrict__ Wout, const float* __restrict__ bout,
    const __bf16* __restrict__ hn_hi, const __bf16* __restrict__ hn_lo,
    float* __restrict__ logits) {
  const int v0 = blockIdx.x * 64;
  const int t = threadIdx.x;
  const int wv = t >> 6;
  const int l = t & 63;
  const int l15 = l & 15;
  const int lg = l >> 4;

  __shared__ __bf16 Ah[8 * 2048];
  __shared__ __bf16 Al[8 * 2048];

  {
    const int chunk = l & 3;
#pragma unroll
    for (int ss = 0; ss < 2; ++ss) {
      const int sub = wv * 2 + ss;
#pragma unroll
      for (int i = 0; i < 4; ++i) {
        const int row = i * 16 + (l >> 2);
        const int v = v0 + row;
        const int vc = v < V_ ? v : V_ - 1;
        const float* gp = Wout + (size_t)vc * H_ + sub * 32 + chunk * 8;
        const float4 f0 = *reinterpret_cast<const float4*>(gp);
        const float4 f1 = *reinterpret_cast<const float4*>(gp + 4);
        const int slot = (chunk + (row >> 1)) & 3;
        float xv[8] = {f0.x, f0.y, f0.z, f0.w, f1.x, f1.y, f1.z, f1.w};
        bf16x8 h8, l8;
#pragma unroll
        for (int j = 0; j < 8; ++j) {
          const __bf16 hh = (__bf16)xv[j];
          h8[j] = hh;
          l8[j] = (__bf16)(xv[j] - (float)hh);
        }
        *reinterpret_cast<bf16x8*>(&Ah[sub * 2048 + row * 32 + slot * 8]) = h8;
        *reinterpret_cast<bf16x8*>(&Al[sub * 2048 + row * 32 + slot * 8]) = l8;
      }
    }
  }
  __syncthreads();

  f32x4 acc[4];
#pragma unroll
  for (int i = 0; i < 4; ++i) acc[i] = (f32x4)(0.f);
  const int col = wv * 16 + l15;  // batch col
#pragma unroll
  for (int k0 = 0; k0 < H_; k0 += 32) {
    const int sub = k0 >> 5;
    const bf16x8 bh = *reinterpret_cast<const bf16x8*>(hn_hi + (size_t)col * H_ + k0 + lg * 8);
    const bf16x8 bl = *reinterpret_cast<const bf16x8*>(hn_lo + (size_t)col * H_ + k0 + lg * 8);
    bf16x8 ah[4], al[4];
#pragma unroll
    for (int rf = 0; rf < 4; ++rf) {
      const int r = rf * 16 + l15;
      const int slot = (lg + (r >> 1)) & 3;
      ah[rf] = *reinterpret_cast<const bf16x8*>(&Ah[sub * 2048 + r * 32 + slot * 8]);
      al[rf] = *reinterpret_cast<const bf16x8*>(&Al[sub * 2048 + r * 32 + slot * 8]);
    }
#pragma unroll
    for (int rf = 0; rf < 4; ++rf) {
      acc[rf] = mfma16(ah[rf], bh, acc[rf]);
      acc[rf] = mfma16(al[rf], bh, acc[rf]);
      acc[rf] = mfma16(ah[rf], bl, acc[rf]);
    }
  }
#pragma unroll
  for (int rf = 0; rf < 4; ++rf)
#pragma unroll
    for (int reg = 0; reg < 4; ++reg) {
      const int v = v0 + rf * 16 + lg * 4 + reg;
      if (v < V_) logits[(size_t)col * V_ + v] = acc[rf][reg] + bout[v];
    }
}

extern "C" void kernel_launch(void* const* d_in, const int* in_sizes, int n_in,
                              void* d_out, int out_size, void* d_ws, size_t ws_size,
                              hipStream_t stream) {
  const int*   inp  = (const int*)  d_in[0];
  const float* enc  = (const float*)d_in[2];
  const float* emb  = (const float*)d_in[3];
  const float* U    = (const float*)d_in[4];
  const float* W    = (const float*)d_in[5];
  const float* v    = (const float*)d_in[6];
  const float* W_ih = (const float*)d_in[7];
  const float* W_hh = (const float*)d_in[8];
  const float* b_ih = (const float*)d_in[9];
  const float* b_hh = (const float*)d_in[10];
  const float* Wout = (const float*)d_in[11];
  const float* bout = (const float*)d_in[12];

  float* logits = (float*)d_out;
  float* out_h  = logits + (size_t)B_ * V_;

  float* ws     = (float*)d_ws;
  __bf16* wt_hi = (__bf16*)ws;                 // H*H bf16
  __bf16* wt_lo = wt_hi + (size_t)H_ * H_;     // H*H bf16
  float* xU   = ws + 65536;                    // after 256KB
  float* xWih = xU + B_ * H_;
  float* e    = xWih + B_ * H_;                // B*S
  float* part = e + (size_t)B_ * S_;           // NCH*B*H
  __bf16* hn_hi = (__bf16*)(part + (size_t)NCH * B_ * H_);
  __bf16* hn_lo = hn_hi + (size_t)B_ * H_;

  prep_k<<<dim3(B_), dim3(256), 0, stream>>>(inp, emb, U, W_ih, b_ih, b_hh, xU, xWih);
  prep_w<<<dim3(H_ * H_ / 256), dim3(256), 0, stream>>>(W, wt_hi, wt_lo);
  attn_mfma<<<dim3(S_ / 64, B_), dim3(512), 0, stream>>>(enc, wt_hi, wt_lo, xU, v, e);
  ctx_partial<<<dim3(NCH, B_), dim3(256), 0, stream>>>(enc, e, part);
  hnew_k<<<dim3(B_), dim3(256), 0, stream>>>(part, xWih, W_hh, out_h, hn_hi, hn_lo);
  logits_mfma<<<dim3((V_ + 63) / 64), dim3(256), 0, stream>>>(Wout, bout, hn_hi, hn_lo, logits);
}

// Round 4
// 150.469 us; speedup vs baseline: 3.4757x; 1.0450x over previous
//
#include <hip/hip_runtime.h>
#include <hip/hip_bf16.h>
#include <math.h>

#define V_ 50000
#define E_ 256
#define H_ 256
#define B_ 64
#define S_ 2048
#define NCHK 32            // S/64 score chunks

typedef __attribute__((ext_vector_type(4))) float f32x4;
typedef __attribute__((ext_vector_type(8))) __bf16 bf16x8;
typedef __attribute__((ext_vector_type(4))) __bf16 bf16x4;

static __device__ __forceinline__ f32x4 mfma16(bf16x8 a, bf16x8 b, f32x4 c) {
  return __builtin_amdgcn_mfma_f32_16x16x32_bf16(a, b, c, 0, 0, 0);
}
static __device__ __forceinline__ float fast_tanh(float x) {
  const float e2 = __expf(2.0f * x);
  return 1.0f - 2.0f / (e2 + 1.0f);
}
#define PIPE_BARRIER()                                  \
  do {                                                  \
    __builtin_amdgcn_sched_barrier(0);                  \
    asm volatile("s_waitcnt lgkmcnt(0)");               \
    __builtin_amdgcn_s_barrier();                       \
    __builtin_amdgcn_sched_barrier(0);                  \
  } while (0)

// ---------------- prep: xU = x@U ; xWih = x@W_ih^T + b_ih + b_hh ----------------
__global__ __launch_bounds__(256) void prep_k(
    const int* __restrict__ inp, const float* __restrict__ emb,
    const float* __restrict__ U, const float* __restrict__ W_ih,
    const float* __restrict__ b_ih, const float* __restrict__ b_hh,
    float* __restrict__ xU, float* __restrict__ xWih) {
  const int b = blockIdx.x, h = threadIdx.x;
  __shared__ float xs[H_];
  xs[h] = emb[(size_t)inp[b] * E_ + h];
  __syncthreads();
  float au = 0.f, aw = 0.f;
  const float* __restrict__ wir = W_ih + (size_t)h * E_;
  for (int k = 0; k < H_; k += 4) {
    const float4 x4 = *reinterpret_cast<const float4*>(&xs[k]);
    const float4 w4 = *reinterpret_cast<const float4*>(wir + k);
    aw = fmaf(x4.x, w4.x, aw); aw = fmaf(x4.y, w4.y, aw);
    aw = fmaf(x4.z, w4.z, aw); aw = fmaf(x4.w, w4.w, aw);
    au = fmaf(x4.x, U[(size_t)(k + 0) * H_ + h], au);
    au = fmaf(x4.y, U[(size_t)(k + 1) * H_ + h], au);
    au = fmaf(x4.z, U[(size_t)(k + 2) * H_ + h], au);
    au = fmaf(x4.w, U[(size_t)(k + 3) * H_ + h], au);
  }
  xU[b * H_ + h] = au;
  xWih[b * H_ + h] = aw + b_ih[h] + b_hh[h];
}

// ---------------- prep W: transposed hi/lo bf16 tables Wt[n][k] ----------------
__global__ __launch_bounds__(256) void prep_w(
    const float* __restrict__ W, __bf16* __restrict__ wt_hi, __bf16* __restrict__ wt_lo) {
  const int idx = blockIdx.x * 256 + threadIdx.x;
  const int n = idx >> 8, k = idx & 255;
  const float w = W[(size_t)k * H_ + n];
  const __bf16 h = (__bf16)w;
  wt_hi[(size_t)n * H_ + k] = h;
  wt_lo[(size_t)n * H_ + k] = (__bf16)(w - (float)h);
}

// ---------------- fused attention: scores (MFMA) + softmax partials + ctx partials ----------------
// block (c, b): 64 s-rows, 512 thr. Pipelined dbuf LDS K-loop, raw barriers (no vmcnt drain).
__global__ __launch_bounds__(512)
__attribute__((amdgpu_waves_per_eu(4, 4)))
void attn_fused(
    const float* __restrict__ enc, const __bf16* __restrict__ wt_hi,
    const __bf16* __restrict__ wt_lo, const float* __restrict__ xU,
    const float* __restrict__ vv, float* __restrict__ ctxp,
    float* __restrict__ mlout) {
  const int c = blockIdx.x, b = blockIdx.y;
  const int s0 = c * 64;
  const int t = threadIdx.x;
  const int wv = t >> 6;
  const int l = t & 63;
  const int l15 = l & 15;
  const int lg = l >> 4;

  __shared__ __bf16 Ah[2][64 * 32];
  __shared__ __bf16 Al[2][64 * 32];
  __shared__ float ered[8][64];
  __shared__ float wgt[64];
  __shared__ float mlL[2];
  __shared__ float red2[2][256];

  const float* __restrict__ encB = enc + ((size_t)b * S_ + s0) * H_;

  // staging geometry: thread -> (row, quarter-chunk)
  const int arow = t >> 3;       // 0..63
  const int qc = t & 7;          // float4 index within 32-col sub-tile
  const int wslot = ((qc >> 1) + (arow >> 1)) & 3;
  const int woff = arow * 32 + wslot * 8 + (qc & 1) * 4;
  const float* __restrict__ aptr = encB + (size_t)arow * H_ + qc * 4;

  float4 f[8];
#pragma unroll
  for (int k = 0; k < 4; ++k)
    f[k] = *reinterpret_cast<const float4*>(aptr + k * 32);

  // write sub 0 to buf 0
  {
    bf16x4 h4, l4;
    const float xv[4] = {f[0].x, f[0].y, f[0].z, f[0].w};
#pragma unroll
    for (int j = 0; j < 4; ++j) {
      const __bf16 hh = (__bf16)xv[j];
      h4[j] = hh;
      l4[j] = (__bf16)(xv[j] - (float)hh);
    }
    *reinterpret_cast<bf16x4*>(&Ah[0][woff]) = h4;
    *reinterpret_cast<bf16x4*>(&Al[0][woff]) = l4;
  }

  const int colb = wv * 32;
  bf16x8 bh[2][2], bl[2][2];
#pragma unroll
  for (int cf = 0; cf < 2; ++cf) {
    const int col = colb + cf * 16 + l15;
    bh[0][cf] = *reinterpret_cast<const bf16x8*>(wt_hi + (size_t)col * H_ + lg * 8);
    bl[0][cf] = *reinterpret_cast<const bf16x8*>(wt_lo + (size_t)col * H_ + lg * 8);
  }

  f32x4 acc[4][2];
#pragma unroll
  for (int i = 0; i < 4; ++i)
#pragma unroll
    for (int j = 0; j < 2; ++j) acc[i][j] = (f32x4)(0.f);

  PIPE_BARRIER();

#pragma unroll
  for (int k = 0; k < 8; ++k) {
    const int cb = k & 1;
    // prefetch A f32 (distance 4)
    if (k < 4)
      f[k + 4] = *reinterpret_cast<const float4*>(aptr + (k + 4) * 32);
    // prefetch B for next sub-tile
    if (k < 7) {
#pragma unroll
      for (int cf = 0; cf < 2; ++cf) {
        const int col = colb + cf * 16 + l15;
        bh[cb ^ 1][cf] = *reinterpret_cast<const bf16x8*>(
            wt_hi + (size_t)col * H_ + (k + 1) * 32 + lg * 8);
        bl[cb ^ 1][cf] = *reinterpret_cast<const bf16x8*>(
            wt_lo + (size_t)col * H_ + (k + 1) * 32 + lg * 8);
      }
    }
    // convert + write next A sub-tile into the other buffer
    if (k < 7) {
      bf16x4 h4, l4;
      const float xv[4] = {f[k + 1].x, f[k + 1].y, f[k + 1].z, f[k + 1].w};
#pragma unroll
      for (int j = 0; j < 4; ++j) {
        const __bf16 hh = (__bf16)xv[j];
        h4[j] = hh;
        l4[j] = (__bf16)(xv[j] - (float)hh);
      }
      *reinterpret_cast<bf16x4*>(&Ah[cb ^ 1][woff]) = h4;
      *reinterpret_cast<bf16x4*>(&Al[cb ^ 1][woff]) = l4;
    }
    // A fragments for sub k
    bf16x8 ah[4], al[4];
#pragma unroll
    for (int rf = 0; rf < 4; ++rf) {
      const int r = rf * 16 + l15;
      const int slot = (lg + (r >> 1)) & 3;
      ah[rf] = *reinterpret_cast<const bf16x8*>(&Ah[cb][r * 32 + slot * 8]);
      al[rf] = *reinterpret_cast<const bf16x8*>(&Al[cb][r * 32 + slot * 8]);
    }
#pragma unroll
    for (int rf = 0; rf < 4; ++rf)
#pragma unroll
      for (int cf = 0; cf < 2; ++cf) {
        acc[rf][cf] = mfma16(ah[rf], bh[cb][cf], acc[rf][cf]);
        acc[rf][cf] = mfma16(al[rf], bh[cb][cf], acc[rf][cf]);
        acc[rf][cf] = mfma16(ah[rf], bl[cb][cf], acc[rf][cf]);
      }
    PIPE_BARRIER();
  }

  // epilogue: tanh + v-dot + 16-lane reduce
  float part[4][4];
#pragma unroll
  for (int rf = 0; rf < 4; ++rf)
#pragma unroll
    for (int reg = 0; reg < 4; ++reg) part[rf][reg] = 0.f;
#pragma unroll
  for (int cf = 0; cf < 2; ++cf) {
    const int col = colb + cf * 16 + l15;
    const float xu = xU[b * H_ + col];
    const float vw = vv[col];
#pragma unroll
    for (int rf = 0; rf < 4; ++rf)
#pragma unroll
      for (int reg = 0; reg < 4; ++reg)
        part[rf][reg] += fast_tanh(xu + acc[rf][cf][reg]) * vw;
  }
#pragma unroll
  for (int o = 1; o < 16; o <<= 1)
#pragma unroll
    for (int rf = 0; rf < 4; ++rf)
#pragma unroll
      for (int reg = 0; reg < 4; ++reg)
        part[rf][reg] += __shfl_xor(part[rf][reg], o);
  if (l15 == 0) {
#pragma unroll
    for (int rf = 0; rf < 4; ++rf)
#pragma unroll
      for (int reg = 0; reg < 4; ++reg)
        ered[wv][rf * 16 + lg * 4 + reg] = part[rf][reg];
  }
  __syncthreads();

  // wave 0: per-chunk softmax stats + weights
  if (t < 64) {
    float es = 0.f;
#pragma unroll
    for (int w = 0; w < 8; ++w) es += ered[w][t];
    float m = es;
#pragma unroll
    for (int o = 1; o < 64; o <<= 1) m = fmaxf(m, __shfl_xor(m, o));
    const float w = __expf(es - m);
    float lsum = w;
#pragma unroll
    for (int o = 1; o < 64; o <<= 1) lsum += __shfl_xor(lsum, o);
    wgt[t] = w;
    if (t == 0) { mlL[0] = m; mlL[1] = lsum; }
  }
  __syncthreads();

  // ctx partials: re-read own tile (L2-hot), weight, 2-group reduce
  {
    const int g = t >> 8, h = t & 255;
    const float* __restrict__ ep = encB + (size_t)(g * 32) * H_ + h;
    float a0 = 0.f;
#pragma unroll 8
    for (int s2 = 0; s2 < 32; ++s2)
      a0 = fmaf(wgt[g * 32 + s2], ep[(size_t)s2 * H_], a0);
    red2[g][h] = a0;
  }
  __syncthreads();
  if (t < 256)
    ctxp[((size_t)c * B_ + b) * H_ + t] = red2[0][t] + red2[1][t];
  if (t == 0) {
    mlout[(c * B_ + b) * 2 + 0] = mlL[0];
    mlout[(c * B_ + b) * 2 + 1] = mlL[1];
  }
}

// ---------------- flash combine + h_new GEMV ----------------
__global__ __launch_bounds__(256) void combine_hnew(
    const float* __restrict__ ctxp, const float* __restrict__ mlout,
    const float* __restrict__ xWih, const float* __restrict__ W_hh,
    float* __restrict__ out_h, __bf16* __restrict__ hn_hi,
    __bf16* __restrict__ hn_lo) {
  const int b = blockIdx.x, h = threadIdx.x;
  __shared__ float cs[H_];
  float M = -3.4e38f;
#pragma unroll
  for (int cc = 0; cc < NCHK; ++cc) M = fmaxf(M, mlout[(cc * B_ + b) * 2]);
  float num = 0.f, den = 0.f;
#pragma unroll
  for (int cc = 0; cc < NCHK; ++cc) {
    const float mw = __expf(mlout[(cc * B_ + b) * 2] - M);
    den = fmaf(mw, mlout[(cc * B_ + b) * 2 + 1], den);
    num = fmaf(mw, ctxp[((size_t)cc * B_ + b) * H_ + h], num);
  }
  cs[h] = num / den;
  __syncthreads();
  const float* __restrict__ wr = W_hh + (size_t)h * H_;
  float a = xWih[b * H_ + h];
  for (int k = 0; k < H_; k += 4) {
    const float4 w4 = *reinterpret_cast<const float4*>(wr + k);
    const float4 c4 = *reinterpret_cast<const float4*>(&cs[k]);
    a = fmaf(c4.x, w4.x, a); a = fmaf(c4.y, w4.y, a);
    a = fmaf(c4.z, w4.z, a); a = fmaf(c4.w, w4.w, a);
  }
  const float hv = fast_tanh(a);
  out_h[b * H_ + h] = hv;
  const __bf16 hh = (__bf16)hv;
  hn_hi[b * H_ + h] = hh;
  hn_lo[b * H_ + h] = (__bf16)(hv - (float)hh);
}

// ---------------- logits = h_new @ W_out^T + b_out via MFMA ----------------
__global__ __launch_bounds__(256, 4) void logits_mfma(
    const float* __restrict__ Wout, const float* __restrict__ bout,
    const __bf16* __restrict__ hn_hi, const __bf16* __restrict__ hn_lo,
    float* __restrict__ logits) {
  const int v0 = blockIdx.x * 64;
  const int t = threadIdx.x;
  const int wv = t >> 6;
  const int l = t & 63;
  const int l15 = l & 15;
  const int lg = l >> 4;

  __shared__ __bf16 Ah[8 * 2048];
  __shared__ __bf16 Al[8 * 2048];

  {
    const int chunk = l & 3;
#pragma unroll
    for (int ss = 0; ss < 2; ++ss) {
      const int sub = wv * 2 + ss;
#pragma unroll
      for (int i = 0; i < 4; ++i) {
        const int row = i * 16 + (l >> 2);
        const int v = v0 + row;
        const int vc = v < V_ ? v : V_ - 1;
        const float* gp = Wout + (size_t)vc * H_ + sub * 32 + chunk * 8;
        const float4 f0 = *reinterpret_cast<const float4*>(gp);
        const float4 f1 = *reinterpret_cast<const float4*>(gp + 4);
        const int slot = (chunk + (row >> 1)) & 3;
        float xv[8] = {f0.x, f0.y, f0.z, f0.w, f1.x, f1.y, f1.z, f1.w};
        bf16x8 h8, l8;
#pragma unroll
        for (int j = 0; j < 8; ++j) {
          const __bf16 hh = (__bf16)xv[j];
          h8[j] = hh;
          l8[j] = (__bf16)(xv[j] - (float)hh);
        }
        *reinterpret_cast<bf16x8*>(&Ah[sub * 2048 + row * 32 + slot * 8]) = h8;
        *reinterpret_cast<bf16x8*>(&Al[sub * 2048 + row * 32 + slot * 8]) = l8;
      }
    }
  }
  __syncthreads();

  f32x4 acc[4];
#pragma unroll
  for (int i = 0; i < 4; ++i) acc[i] = (f32x4)(0.f);
  const int col = wv * 16 + l15;
#pragma unroll
  for (int k0 = 0; k0 < H_; k0 += 32) {
    const int sub = k0 >> 5;
    const bf16x8 bhv = *reinterpret_cast<const bf16x8*>(hn_hi + (size_t)col * H_ + k0 + lg * 8);
    const bf16x8 blv = *reinterpret_cast<const bf16x8*>(hn_lo + (size_t)col * H_ + k0 + lg * 8);
    bf16x8 ah[4], al[4];
#pragma unroll
    for (int rf = 0; rf < 4; ++rf) {
      const int r = rf * 16 + l15;
      const int slot = (lg + (r >> 1)) & 3;
      ah[rf] = *reinterpret_cast<const bf16x8*>(&Ah[sub * 2048 + r * 32 + slot * 8]);
      al[rf] = *reinterpret_cast<const bf16x8*>(&Al[sub * 2048 + r * 32 + slot * 8]);
    }
#pragma unroll
    for (int rf = 0; rf < 4; ++rf) {
      acc[rf] = mfma16(ah[rf], bhv, acc[rf]);
      acc[rf] = mfma16(al[rf], bhv, acc[rf]);
      acc[rf] = mfma16(ah[rf], blv, acc[rf]);
    }
  }
#pragma unroll
  for (int rf = 0; rf < 4; ++rf)
#pragma unroll
    for (int reg = 0; reg < 4; ++reg) {
      const int v = v0 + rf * 16 + lg * 4 + reg;
      if (v < V_) logits[(size_t)col * V_ + v] = acc[rf][reg] + bout[v];
    }
}

extern "C" void kernel_launch(void* const* d_in, const int* in_sizes, int n_in,
                              void* d_out, int out_size, void* d_ws, size_t ws_size,
                              hipStream_t stream) {
  const int*   inp  = (const int*)  d_in[0];
  const float* enc  = (const float*)d_in[2];
  const float* emb  = (const float*)d_in[3];
  const float* U    = (const float*)d_in[4];
  const float* W    = (const float*)d_in[5];
  const float* v    = (const float*)d_in[6];
  const float* W_ih = (const float*)d_in[7];
  const float* W_hh = (const float*)d_in[8];
  const float* b_ih = (const float*)d_in[9];
  const float* b_hh = (const float*)d_in[10];
  const float* Wout = (const float*)d_in[11];
  const float* bout = (const float*)d_in[12];

  float* logits = (float*)d_out;
  float* out_h  = logits + (size_t)B_ * V_;

  float* ws     = (float*)d_ws;
  __bf16* wt_hi = (__bf16*)ws;                      // 64K bf16
  __bf16* wt_lo = wt_hi + (size_t)H_ * H_;          // 64K bf16
  float* xU    = ws + 65536;
  float* xWih  = xU + B_ * H_;
  float* ctxp  = xWih + B_ * H_;                    // NCHK*B*H
  float* mlout = ctxp + (size_t)NCHK * B_ * H_;     // NCHK*B*2
  __bf16* hn_hi = (__bf16*)(mlout + NCHK * B_ * 2);
  __bf16* hn_lo = hn_hi + (size_t)B_ * H_;

  prep_k<<<dim3(B_), dim3(256), 0, stream>>>(inp, emb, U, W_ih, b_ih, b_hh, xU, xWih);
  prep_w<<<dim3(H_ * H_ / 256), dim3(256), 0, stream>>>(W, wt_hi, wt_lo);
  attn_fused<<<dim3(NCHK, B_), dim3(512), 0, stream>>>(enc, wt_hi, wt_lo, xU, v, ctxp, mlout);
  combine_hnew<<<dim3(B_), dim3(256), 0, stream>>>(ctxp, mlout, xWih, W_hh, out_h, hn_hi, hn_lo);
  logits_mfma<<<dim3((V_ + 63) / 64), dim3(256), 0, stream>>>(Wout, bout, hn_hi, hn_lo, logits);
}

// Round 5
// 134.337 us; speedup vs baseline: 3.8930x; 1.1201x over previous
//
#include <hip/hip_runtime.h>
#include <hip/hip_bf16.h>
#include <math.h>

#define V_ 50000
#define E_ 256
#define H_ 256
#define B_ 64
#define S_ 2048
#define NCHK 32            // S/64 score chunks

typedef __attribute__((ext_vector_type(4))) float f32x4;
typedef __attribute__((ext_vector_type(8))) __bf16 bf16x8;

static __device__ __forceinline__ f32x4 mfma16(bf16x8 a, bf16x8 b, f32x4 c) {
  return __builtin_amdgcn_mfma_f32_16x16x32_bf16(a, b, c, 0, 0, 0);
}
static __device__ __forceinline__ float fast_tanh(float x) {
  const float e2 = __expf(2.0f * x);
  return 1.0f - 2.0f / (e2 + 1.0f);
}
// Swizzled byte offset in a [64][256] bf16 tile (row stride 512B).
// slab = 64B k-granule (32 bf16), g = 16B sub-granule. Slab rotated by row
// (breaks 512B-stride bank wrap), sub-granule rotated by row+row>>2
// (measured-style 2-way-max pattern).
static __device__ __forceinline__ int tile_off(int row, int slab, int g) {
  return row * 512 + (((slab + row) & 7) << 6) + (((g + row + (row >> 2)) & 3) << 4);
}

// ---------------- prep: xU = x@U ; xWih = x@W_ih^T + b_ih + b_hh ----------------
__global__ __launch_bounds__(256) void prep_k(
    const int* __restrict__ inp, const float* __restrict__ emb,
    const float* __restrict__ U, const float* __restrict__ W_ih,
    const float* __restrict__ b_ih, const float* __restrict__ b_hh,
    float* __restrict__ xU, float* __restrict__ xWih) {
  const int b = blockIdx.x, h = threadIdx.x;
  __shared__ float xs[H_];
  xs[h] = emb[(size_t)inp[b] * E_ + h];
  __syncthreads();
  float au = 0.f, aw = 0.f;
  const float* __restrict__ wir = W_ih + (size_t)h * E_;
  for (int k = 0; k < H_; k += 4) {
    const float4 x4 = *reinterpret_cast<const float4*>(&xs[k]);
    const float4 w4 = *reinterpret_cast<const float4*>(wir + k);
    aw = fmaf(x4.x, w4.x, aw); aw = fmaf(x4.y, w4.y, aw);
    aw = fmaf(x4.z, w4.z, aw); aw = fmaf(x4.w, w4.w, aw);
    au = fmaf(x4.x, U[(size_t)(k + 0) * H_ + h], au);
    au = fmaf(x4.y, U[(size_t)(k + 1) * H_ + h], au);
    au = fmaf(x4.z, U[(size_t)(k + 2) * H_ + h], au);
    au = fmaf(x4.w, U[(size_t)(k + 3) * H_ + h], au);
  }
  xU[b * H_ + h] = au;
  xWih[b * H_ + h] = aw + b_ih[h] + b_hh[h];
}

// ---------------- prep W: transposed hi/lo bf16 tables Wt[n][k] ----------------
__global__ __launch_bounds__(256) void prep_w(
    const float* __restrict__ W, __bf16* __restrict__ wt_hi, __bf16* __restrict__ wt_lo) {
  const int idx = blockIdx.x * 256 + threadIdx.x;
  const int n = idx >> 8, k = idx & 255;
  const float w = W[(size_t)k * H_ + n];
  const __bf16 h = (__bf16)w;
  wt_hi[(size_t)n * H_ + k] = h;
  wt_lo[(size_t)n * H_ + k] = (__bf16)(w - (float)h);
}

// ---------------- fused attention: scores (2-term MFMA) + softmax + ctx partials ----------------
// block (c,b): 64 s-rows x 256 cols, 256 thr (4 waves, each 64x64).
// A-tile: full 64x256 bf16 in LDS (8 slabs), staged slab-by-slab under compute.
__global__ __launch_bounds__(256) void attn_fused(
    const float* __restrict__ enc, const __bf16* __restrict__ wt_hi,
    const __bf16* __restrict__ wt_lo, const float* __restrict__ xU,
    const float* __restrict__ vv, float* __restrict__ ctxp,
    float* __restrict__ mlout) {
  const int c = blockIdx.x, b = blockIdx.y;
  const int s0 = c * 64;
  const int t = threadIdx.x;
  const int wv = t >> 6, l = t & 63, l15 = l & 15, lg = l >> 4;

  __shared__ __bf16 Abuf[64 * 256];   // 32 KB
  __shared__ float ered[4][64];
  __shared__ float wgt[64];
  __shared__ float mlL[2];
  char* Ab = (char*)Abuf;

  // staging map: 4 consecutive lanes cover one row's 128B slab (coalesced)
  const int srow = t >> 2, sg = t & 3;
  const float* __restrict__ encR = enc + ((size_t)b * S_ + s0 + srow) * H_ + sg * 8;

  // prologue: stage slab 0
  {
    const float4 f0 = *reinterpret_cast<const float4*>(encR);
    const float4 f1 = *reinterpret_cast<const float4*>(encR + 4);
    const float xv[8] = {f0.x, f0.y, f0.z, f0.w, f1.x, f1.y, f1.z, f1.w};
    bf16x8 h8;
#pragma unroll
    for (int j = 0; j < 8; ++j) h8[j] = (__bf16)xv[j];
    *reinterpret_cast<bf16x8*>(Ab + tile_off(srow, 0, sg)) = h8;
  }
  __syncthreads();

  f32x4 acc[4][4];
#pragma unroll
  for (int i = 0; i < 4; ++i)
#pragma unroll
    for (int j = 0; j < 4; ++j) acc[i][j] = (f32x4)(0.f);

#pragma unroll
  for (int k = 0; k < 8; ++k) {
    // B fragments first (L2-resident W tables) so MFMA's vmcnt wait
    // does not cover the HBM stage loads issued after.
    bf16x8 bh[4], bl[4];
#pragma unroll
    for (int cf = 0; cf < 4; ++cf) {
      const int col = wv * 64 + cf * 16 + l15;
      const size_t off = (size_t)col * H_ + k * 32 + lg * 8;
      bh[cf] = *reinterpret_cast<const bf16x8*>(wt_hi + off);
      bl[cf] = *reinterpret_cast<const bf16x8*>(wt_lo + off);
    }
    // stage loads for slab k+1 (HBM), consumed at end of step
    float4 f0, f1;
    if (k < 7) {
      f0 = *reinterpret_cast<const float4*>(encR + (k + 1) * 32);
      f1 = *reinterpret_cast<const float4*>(encR + (k + 1) * 32 + 4);
    }
    // A fragments for slab k
    bf16x8 ah[4];
#pragma unroll
    for (int rf = 0; rf < 4; ++rf)
      ah[rf] = *reinterpret_cast<const bf16x8*>(Ab + tile_off(rf * 16 + l15, k, lg));
    // 2-term MFMA: enc_bf16 * (W_hi + W_lo)
#pragma unroll
    for (int rf = 0; rf < 4; ++rf)
#pragma unroll
      for (int cf = 0; cf < 4; ++cf) {
        acc[rf][cf] = mfma16(ah[rf], bh[cf], acc[rf][cf]);
        acc[rf][cf] = mfma16(ah[rf], bl[cf], acc[rf][cf]);
      }
    // convert + write slab k+1
    if (k < 7) {
      const float xv[8] = {f0.x, f0.y, f0.z, f0.w, f1.x, f1.y, f1.z, f1.w};
      bf16x8 h8;
#pragma unroll
      for (int j = 0; j < 8; ++j) h8[j] = (__bf16)xv[j];
      *reinterpret_cast<bf16x8*>(Ab + tile_off(srow, k + 1, sg)) = h8;
    }
    __syncthreads();
  }

  // epilogue: tanh + v-dot + 16-lane reduce
  float part[4][4];
#pragma unroll
  for (int rf = 0; rf < 4; ++rf)
#pragma unroll
    for (int reg = 0; reg < 4; ++reg) part[rf][reg] = 0.f;
#pragma unroll
  for (int cf = 0; cf < 4; ++cf) {
    const int col = wv * 64 + cf * 16 + l15;
    const float xu = xU[b * H_ + col];
    const float vw = vv[col];
#pragma unroll
    for (int rf = 0; rf < 4; ++rf)
#pragma unroll
      for (int reg = 0; reg < 4; ++reg)
        part[rf][reg] += fast_tanh(xu + acc[rf][cf][reg]) * vw;
  }
#pragma unroll
  for (int o = 1; o < 16; o <<= 1)
#pragma unroll
    for (int rf = 0; rf < 4; ++rf)
#pragma unroll
      for (int reg = 0; reg < 4; ++reg)
        part[rf][reg] += __shfl_xor(part[rf][reg], o);
  if (l15 == 0) {
#pragma unroll
    for (int rf = 0; rf < 4; ++rf)
#pragma unroll
      for (int reg = 0; reg < 4; ++reg)
        ered[wv][rf * 16 + lg * 4 + reg] = part[rf][reg];
  }
  __syncthreads();

  // wave 0: per-chunk softmax stats + weights
  if (t < 64) {
    const float es = ered[0][t] + ered[1][t] + ered[2][t] + ered[3][t];
    float m = es;
#pragma unroll
    for (int o = 1; o < 64; o <<= 1) m = fmaxf(m, __shfl_xor(m, o));
    const float w = __expf(es - m);
    float lsum = w;
#pragma unroll
    for (int o = 1; o < 64; o <<= 1) lsum += __shfl_xor(lsum, o);
    wgt[t] = w;
    if (t == 0) { mlL[0] = m; mlL[1] = lsum; }
  }
  __syncthreads();

  // ctx partials from the LDS bf16 tile: thread t owns feature h = t
  {
    const int j = t & 7, gg = (t >> 3) & 3, ks = t >> 5;
    float a0 = 0.f, a1 = 0.f;
#pragma unroll 4
    for (int s = 0; s < 64; s += 2) {
      a0 = fmaf(wgt[s],     (float)Abuf[(tile_off(s,     ks, gg) >> 1) + j], a0);
      a1 = fmaf(wgt[s + 1], (float)Abuf[(tile_off(s + 1, ks, gg) >> 1) + j], a1);
    }
    ctxp[((size_t)c * B_ + b) * H_ + t] = a0 + a1;
  }
  if (t == 0) {
    mlout[(c * B_ + b) * 2 + 0] = mlL[0];
    mlout[(c * B_ + b) * 2 + 1] = mlL[1];
  }
}

// ---------------- flash combine + h_new GEMV ----------------
__global__ __launch_bounds__(256) void combine_hnew(
    const float* __restrict__ ctxp, const float* __restrict__ mlout,
    const float* __restrict__ xWih, const float* __restrict__ W_hh,
    float* __restrict__ out_h, __bf16* __restrict__ hn) {
  const int b = blockIdx.x, h = threadIdx.x;
  __shared__ float cs[H_];
  float M = -3.4e38f;
#pragma unroll
  for (int cc = 0; cc < NCHK; ++cc) M = fmaxf(M, mlout[(cc * B_ + b) * 2]);
  float num = 0.f, den = 0.f;
#pragma unroll
  for (int cc = 0; cc < NCHK; ++cc) {
    const float mw = __expf(mlout[(cc * B_ + b) * 2] - M);
    den = fmaf(mw, mlout[(cc * B_ + b) * 2 + 1], den);
    num = fmaf(mw, ctxp[((size_t)cc * B_ + b) * H_ + h], num);
  }
  cs[h] = num / den;
  __syncthreads();
  const float* __restrict__ wr = W_hh + (size_t)h * H_;
  float a = xWih[b * H_ + h];
  for (int k = 0; k < H_; k += 4) {
    const float4 w4 = *reinterpret_cast<const float4*>(wr + k);
    const float4 c4 = *reinterpret_cast<const float4*>(&cs[k]);
    a = fmaf(c4.x, w4.x, a); a = fmaf(c4.y, w4.y, a);
    a = fmaf(c4.z, w4.z, a); a = fmaf(c4.w, w4.w, a);
  }
  const float hv = fast_tanh(a);
  out_h[b * H_ + h] = hv;
  hn[b * H_ + h] = (__bf16)hv;
}

// ---------------- logits = h_new @ W_out^T + b_out via pure-bf16 MFMA ----------------
// block: 64 vocab rows x 64 batch cols, 256 thr (4 waves x 16 batch cols).
__global__ __launch_bounds__(256) void logits_mfma(
    const float* __restrict__ Wout, const float* __restrict__ bout,
    const __bf16* __restrict__ hn, float* __restrict__ logits) {
  const int v0 = blockIdx.x * 64;
  const int t = threadIdx.x;
  const int wv = t >> 6, l = t & 63, l15 = l & 15, lg = l >> 4;

  __shared__ __bf16 Wbuf[64 * 256];   // 32 KB
  char* Wb = (char*)Wbuf;

  // stage Wout tile -> bf16 LDS (coalesced: 4 lanes per row-slab)
  {
    const int srow = t >> 2, sg = t & 3;
    const int vc = (v0 + srow) < V_ ? (v0 + srow) : (V_ - 1);
    const float* __restrict__ wr = Wout + (size_t)vc * H_ + sg * 8;
#pragma unroll
    for (int ks = 0; ks < 8; ++ks) {
      const float4 f0 = *reinterpret_cast<const float4*>(wr + ks * 32);
      const float4 f1 = *reinterpret_cast<const float4*>(wr + ks * 32 + 4);
      const float xv[8] = {f0.x, f0.y, f0.z, f0.w, f1.x, f1.y, f1.z, f1.w};
      bf16x8 h8;
#pragma unroll
      for (int j = 0; j < 8; ++j) h8[j] = (__bf16)xv[j];
      *reinterpret_cast<bf16x8*>(Wb + tile_off(srow, ks, sg)) = h8;
    }
  }
  __syncthreads();

  f32x4 acc[4];
#pragma unroll
  for (int i = 0; i < 4; ++i) acc[i] = (f32x4)(0.f);
  const int colb = wv * 16 + l15;   // batch col
#pragma unroll
  for (int k = 0; k < 8; ++k) {
    const bf16x8 bfrag = *reinterpret_cast<const bf16x8*>(hn + (size_t)colb * H_ + k * 32 + lg * 8);
    bf16x8 ah[4];
#pragma unroll
    for (int rf = 0; rf < 4; ++rf)
      ah[rf] = *reinterpret_cast<const bf16x8*>(Wb + tile_off(rf * 16 + l15, k, lg));
#pragma unroll
    for (int rf = 0; rf < 4; ++rf)
      acc[rf] = mfma16(ah[rf], bfrag, acc[rf]);
  }
#pragma unroll
  for (int rf = 0; rf < 4; ++rf) {
    const int v = v0 + rf * 16 + lg * 4;
    if (v < V_) {
      const float4 bo = *reinterpret_cast<const float4*>(bout + v);
      float4 o;
      o.x = acc[rf][0] + bo.x; o.y = acc[rf][1] + bo.y;
      o.z = acc[rf][2] + bo.z; o.w = acc[rf][3] + bo.w;
      *reinterpret_cast<float4*>(logits + (size_t)colb * V_ + v) = o;
    }
  }
}

extern "C" void kernel_launch(void* const* d_in, const int* in_sizes, int n_in,
                              void* d_out, int out_size, void* d_ws, size_t ws_size,
                              hipStream_t stream) {
  const int*   inp  = (const int*)  d_in[0];
  const float* enc  = (const float*)d_in[2];
  const float* emb  = (const float*)d_in[3];
  const float* U    = (const float*)d_in[4];
  const float* W    = (const float*)d_in[5];
  const float* v    = (const float*)d_in[6];
  const float* W_ih = (const float*)d_in[7];
  const float* W_hh = (const float*)d_in[8];
  const float* b_ih = (const float*)d_in[9];
  const float* b_hh = (const float*)d_in[10];
  const float* Wout = (const float*)d_in[11];
  const float* bout = (const float*)d_in[12];

  float* logits = (float*)d_out;
  float* out_h  = logits + (size_t)B_ * V_;

  float* ws     = (float*)d_ws;
  __bf16* wt_hi = (__bf16*)ws;                      // H*H bf16
  __bf16* wt_lo = wt_hi + (size_t)H_ * H_;          // H*H bf16
  float* xU    = ws + 65536;                        // after 256 KB
  float* xWih  = xU + B_ * H_;
  float* ctxp  = xWih + B_ * H_;                    // NCHK*B*H
  float* mlout = ctxp + (size_t)NCHK * B_ * H_;     // NCHK*B*2
  __bf16* hn   = (__bf16*)(mlout + NCHK * B_ * 2);  // B*H bf16

  prep_k<<<dim3(B_), dim3(256), 0, stream>>>(inp, emb, U, W_ih, b_ih, b_hh, xU, xWih);
  prep_w<<<dim3(H_ * H_ / 256), dim3(256), 0, stream>>>(W, wt_hi, wt_lo);
  attn_fused<<<dim3(NCHK, B_), dim3(256), 0, stream>>>(enc, wt_hi, wt_lo, xU, v, ctxp, mlout);
  combine_hnew<<<dim3(B_), dim3(256), 0, stream>>>(ctxp, mlout, xWih, W_hh, out_h, hn);
  logits_mfma<<<dim3((V_ + 63) / 64), dim3(256), 0, stream>>>(Wout, bout, hn, logits);
}

// Round 6
// 133.564 us; speedup vs baseline: 3.9156x; 1.0058x over previous
//
#include <hip/hip_runtime.h>
#include <hip/hip_bf16.h>
#include <math.h>

#define V_ 50000
#define E_ 256
#define H_ 256
#define B_ 64
#define S_ 2048
#define NCHK 32            // S/64 score chunks

typedef __attribute__((ext_vector_type(4))) float f32x4;
typedef __attribute__((ext_vector_type(8))) __bf16 bf16x8;

static __device__ __forceinline__ f32x4 mfma16(bf16x8 a, bf16x8 b, f32x4 c) {
  return __builtin_amdgcn_mfma_f32_16x16x32_bf16(a, b, c, 0, 0, 0);
}
static __device__ __forceinline__ float fast_tanh(float x) {
  const float e2 = __expf(2.0f * x);
  return 1.0f - 2.0f / (e2 + 1.0f);
}

// ---------------- prep: xU = x@U ; xWih = x@W_ih^T + b_ih + b_hh ----------------
__global__ __launch_bounds__(256) void prep_k(
    const int* __restrict__ inp, const float* __restrict__ emb,
    const float* __restrict__ U, const float* __restrict__ W_ih,
    const float* __restrict__ b_ih, const float* __restrict__ b_hh,
    float* __restrict__ xU, float* __restrict__ xWih) {
  const int b = blockIdx.x, h = threadIdx.x;
  __shared__ float xs[H_];
  xs[h] = emb[(size_t)inp[b] * E_ + h];
  __syncthreads();
  float au = 0.f, aw = 0.f;
  const float* __restrict__ wir = W_ih + (size_t)h * E_;
  for (int k = 0; k < H_; k += 4) {
    const float4 x4 = *reinterpret_cast<const float4*>(&xs[k]);
    const float4 w4 = *reinterpret_cast<const float4*>(wir + k);
    aw = fmaf(x4.x, w4.x, aw); aw = fmaf(x4.y, w4.y, aw);
    aw = fmaf(x4.z, w4.z, aw); aw = fmaf(x4.w, w4.w, aw);
    au = fmaf(x4.x, U[(size_t)(k + 0) * H_ + h], au);
    au = fmaf(x4.y, U[(size_t)(k + 1) * H_ + h], au);
    au = fmaf(x4.z, U[(size_t)(k + 2) * H_ + h], au);
    au = fmaf(x4.w, U[(size_t)(k + 3) * H_ + h], au);
  }
  xU[b * H_ + h] = au;
  xWih[b * H_ + h] = aw + b_ih[h] + b_hh[h];
}

// ---------------- prep W: transposed hi/lo bf16 tables Wt[n][k] ----------------
__global__ __launch_bounds__(256) void prep_w(
    const float* __restrict__ W, __bf16* __restrict__ wt_hi, __bf16* __restrict__ wt_lo) {
  const int idx = blockIdx.x * 256 + threadIdx.x;
  const int n = idx >> 8, k = idx & 255;
  const float w = W[(size_t)k * H_ + n];
  const __bf16 h = (__bf16)w;
  wt_hi[(size_t)n * H_ + k] = h;
  wt_lo[(size_t)n * H_ + k] = (__bf16)(w - (float)h);
}

// ---------------- fused attention: scores (2-term MFMA) + softmax + ctx partials ----------------
// block (c,b): 64 s-rows x 256 cols, 256 thr (4 waves, each 64x64).
// Full-tile prologue (1 barrier), barrier-free K-loop with explicit
// double-buffered B prefetch (forces VGPR-resident pipeline depth).
__global__ __launch_bounds__(256, 2) void attn_fused(
    const float* __restrict__ enc, const __bf16* __restrict__ wt_hi,
    const __bf16* __restrict__ wt_lo, const float* __restrict__ xU,
    const float* __restrict__ vv, float* __restrict__ ctxp,
    float* __restrict__ mlout) {
  const int c = blockIdx.x, b = blockIdx.y;
  const int s0 = c * 64;
  const int t = threadIdx.x;
  const int wv = t >> 6, l = t & 63, l15 = l & 15, lg = l >> 4;

  __shared__ __bf16 Asub[8][64][32];   // 32 KB, slot-rotated (round-3 layout, 0 conflicts)
  __shared__ float ered[4][64];
  __shared__ float wgt[64];
  __shared__ float mlL[2];

  // ---- prologue: stage full 64x256 tile as bf16 (16 HBM loads in flight) ----
  const int srow = t >> 2, sg = t & 3;
  const int wslot = (sg + (srow >> 1)) & 3;
  const float* __restrict__ encR = enc + ((size_t)b * S_ + s0 + srow) * H_ + sg * 8;
#pragma unroll
  for (int k = 0; k < 8; ++k) {
    const float4 f0 = *reinterpret_cast<const float4*>(encR + k * 32);
    const float4 f1 = *reinterpret_cast<const float4*>(encR + k * 32 + 4);
    const float xv[8] = {f0.x, f0.y, f0.z, f0.w, f1.x, f1.y, f1.z, f1.w};
    bf16x8 h8;
#pragma unroll
    for (int j = 0; j < 8; ++j) h8[j] = (__bf16)xv[j];
    *reinterpret_cast<bf16x8*>(&Asub[k][srow][wslot * 8]) = h8;
  }
  __syncthreads();

  // ---- barrier-free K-loop, depth-1 explicit B double-buffer ----
  bf16x8 bh[2][4], bl[2][4];
#pragma unroll
  for (int cf = 0; cf < 4; ++cf) {
    const int col = wv * 64 + cf * 16 + l15;
    bh[0][cf] = *reinterpret_cast<const bf16x8*>(wt_hi + (size_t)col * H_ + lg * 8);
    bl[0][cf] = *reinterpret_cast<const bf16x8*>(wt_lo + (size_t)col * H_ + lg * 8);
  }

  f32x4 acc[4][4];
#pragma unroll
  for (int i = 0; i < 4; ++i)
#pragma unroll
    for (int j = 0; j < 4; ++j) acc[i][j] = (f32x4)(0.f);

#pragma unroll
  for (int k = 0; k < 8; ++k) {
    const int cb = k & 1;
    if (k < 7) {
#pragma unroll
      for (int cf = 0; cf < 4; ++cf) {
        const int col = wv * 64 + cf * 16 + l15;
        const size_t off = (size_t)col * H_ + (k + 1) * 32 + lg * 8;
        bh[cb ^ 1][cf] = *reinterpret_cast<const bf16x8*>(wt_hi + off);
        bl[cb ^ 1][cf] = *reinterpret_cast<const bf16x8*>(wt_lo + off);
      }
    }
    bf16x8 ah[4];
#pragma unroll
    for (int rf = 0; rf < 4; ++rf) {
      const int r = rf * 16 + l15;
      const int slot = (lg + (r >> 1)) & 3;
      ah[rf] = *reinterpret_cast<const bf16x8*>(&Asub[k][r][slot * 8]);
    }
#pragma unroll
    for (int rf = 0; rf < 4; ++rf)
#pragma unroll
      for (int cf = 0; cf < 4; ++cf) {
        acc[rf][cf] = mfma16(ah[rf], bh[cb][cf], acc[rf][cf]);
        acc[rf][cf] = mfma16(ah[rf], bl[cb][cf], acc[rf][cf]);
      }
  }

  // ---- epilogue: tanh + v-dot + 16-lane reduce ----
  float part[4][4];
#pragma unroll
  for (int rf = 0; rf < 4; ++rf)
#pragma unroll
    for (int reg = 0; reg < 4; ++reg) part[rf][reg] = 0.f;
#pragma unroll
  for (int cf = 0; cf < 4; ++cf) {
    const int col = wv * 64 + cf * 16 + l15;
    const float xu = xU[b * H_ + col];
    const float vw = vv[col];
#pragma unroll
    for (int rf = 0; rf < 4; ++rf)
#pragma unroll
      for (int reg = 0; reg < 4; ++reg)
        part[rf][reg] += fast_tanh(xu + acc[rf][cf][reg]) * vw;
  }
#pragma unroll
  for (int o = 1; o < 16; o <<= 1)
#pragma unroll
    for (int rf = 0; rf < 4; ++rf)
#pragma unroll
      for (int reg = 0; reg < 4; ++reg)
        part[rf][reg] += __shfl_xor(part[rf][reg], o);
  if (l15 == 0) {
#pragma unroll
    for (int rf = 0; rf < 4; ++rf)
#pragma unroll
      for (int reg = 0; reg < 4; ++reg)
        ered[wv][rf * 16 + lg * 4 + reg] = part[rf][reg];
  }
  __syncthreads();

  // wave 0: per-chunk softmax stats + weights
  if (t < 64) {
    const float es = ered[0][t] + ered[1][t] + ered[2][t] + ered[3][t];
    float m = es;
#pragma unroll
    for (int o = 1; o < 64; o <<= 1) m = fmaxf(m, __shfl_xor(m, o));
    const float w = __expf(es - m);
    float lsum = w;
#pragma unroll
    for (int o = 1; o < 64; o <<= 1) lsum += __shfl_xor(lsum, o);
    wgt[t] = w;
    if (t == 0) { mlL[0] = m; mlL[1] = lsum; }
  }
  __syncthreads();

  // ctx partials from the LDS bf16 tile: thread t owns feature h = t
  {
    const int j = t & 7, g2 = (t >> 3) & 3, ks = t >> 5;
    float a0 = 0.f, a1 = 0.f;
#pragma unroll 4
    for (int s = 0; s < 64; s += 2) {
      a0 = fmaf(wgt[s],     (float)Asub[ks][s][((g2 + (s >> 1)) & 3) * 8 + j], a0);
      a1 = fmaf(wgt[s + 1], (float)Asub[ks][s + 1][((g2 + ((s + 1) >> 1)) & 3) * 8 + j], a1);
    }
    ctxp[((size_t)c * B_ + b) * H_ + t] = a0 + a1;
  }
  if (t == 0) {
    mlout[(c * B_ + b) * 2 + 0] = mlL[0];
    mlout[(c * B_ + b) * 2 + 1] = mlL[1];
  }
}

// ---------------- flash combine + h_new GEMV ----------------
__global__ __launch_bounds__(256) void combine_hnew(
    const float* __restrict__ ctxp, const float* __restrict__ mlout,
    const float* __restrict__ xWih, const float* __restrict__ W_hh,
    float* __restrict__ out_h, __bf16* __restrict__ hn) {
  const int b = blockIdx.x, h = threadIdx.x;
  __shared__ float cs[H_];
  float M = -3.4e38f;
#pragma unroll
  for (int cc = 0; cc < NCHK; ++cc) M = fmaxf(M, mlout[(cc * B_ + b) * 2]);
  float num = 0.f, den = 0.f;
#pragma unroll
  for (int cc = 0; cc < NCHK; ++cc) {
    const float mw = __expf(mlout[(cc * B_ + b) * 2] - M);
    den = fmaf(mw, mlout[(cc * B_ + b) * 2 + 1], den);
    num = fmaf(mw, ctxp[((size_t)cc * B_ + b) * H_ + h], num);
  }
  cs[h] = num / den;
  __syncthreads();
  const float* __restrict__ wr = W_hh + (size_t)h * H_;
  float a = xWih[b * H_ + h];
  for (int k = 0; k < H_; k += 4) {
    const float4 w4 = *reinterpret_cast<const float4*>(wr + k);
    const float4 c4 = *reinterpret_cast<const float4*>(&cs[k]);
    a = fmaf(c4.x, w4.x, a); a = fmaf(c4.y, w4.y, a);
    a = fmaf(c4.z, w4.z, a); a = fmaf(c4.w, w4.w, a);
  }
  const float hv = fast_tanh(a);
  out_h[b * H_ + h] = hv;
  hn[b * H_ + h] = (__bf16)hv;
}

// ---------------- logits = h_new @ W_out^T + b_out via pure-bf16 MFMA ----------------
__global__ __launch_bounds__(256) void logits_mfma(
    const float* __restrict__ Wout, const float* __restrict__ bout,
    const __bf16* __restrict__ hn, float* __restrict__ logits) {
  const int v0 = blockIdx.x * 64;
  const int t = threadIdx.x;
  const int wv = t >> 6, l = t & 63, l15 = l & 15, lg = l >> 4;

  __shared__ __bf16 Wsub[8][64][32];   // 32 KB, same slot-rotated layout

  {
    const int srow = t >> 2, sg = t & 3;
    const int wslot = (sg + (srow >> 1)) & 3;
    const int vc = (v0 + srow) < V_ ? (v0 + srow) : (V_ - 1);
    const float* __restrict__ wr = Wout + (size_t)vc * H_ + sg * 8;
#pragma unroll
    for (int ks = 0; ks < 8; ++ks) {
      const float4 f0 = *reinterpret_cast<const float4*>(wr + ks * 32);
      const float4 f1 = *reinterpret_cast<const float4*>(wr + ks * 32 + 4);
      const float xv[8] = {f0.x, f0.y, f0.z, f0.w, f1.x, f1.y, f1.z, f1.w};
      bf16x8 h8;
#pragma unroll
      for (int j = 0; j < 8; ++j) h8[j] = (__bf16)xv[j];
      *reinterpret_cast<bf16x8*>(&Wsub[ks][srow][wslot * 8]) = h8;
    }
  }
  __syncthreads();

  f32x4 acc[4];
#pragma unroll
  for (int i = 0; i < 4; ++i) acc[i] = (f32x4)(0.f);
  const int colb = wv * 16 + l15;   // batch col
#pragma unroll
  for (int k = 0; k < 8; ++k) {
    const bf16x8 bfrag = *reinterpret_cast<const bf16x8*>(hn + (size_t)colb * H_ + k * 32 + lg * 8);
    bf16x8 ah[4];
#pragma unroll
    for (int rf = 0; rf < 4; ++rf) {
      const int r = rf * 16 + l15;
      const int slot = (lg + (r >> 1)) & 3;
      ah[rf] = *reinterpret_cast<const bf16x8*>(&Wsub[k][r][slot * 8]);
    }
#pragma unroll
    for (int rf = 0; rf < 4; ++rf)
      acc[rf] = mfma16(ah[rf], bfrag, acc[rf]);
  }
#pragma unroll
  for (int rf = 0; rf < 4; ++rf) {
    const int v = v0 + rf * 16 + lg * 4;
    if (v < V_) {
      const float4 bo = *reinterpret_cast<const float4*>(bout + v);
      float4 o;
      o.x = acc[rf][0] + bo.x; o.y = acc[rf][1] + bo.y;
      o.z = acc[rf][2] + bo.z; o.w = acc[rf][3] + bo.w;
      *reinterpret_cast<float4*>(logits + (size_t)colb * V_ + v) = o;
    }
  }
}

extern "C" void kernel_launch(void* const* d_in, const int* in_sizes, int n_in,
                              void* d_out, int out_size, void* d_ws, size_t ws_size,
                              hipStream_t stream) {
  const int*   inp  = (const int*)  d_in[0];
  const float* enc  = (const float*)d_in[2];
  const float* emb  = (const float*)d_in[3];
  const float* U    = (const float*)d_in[4];
  const float* W    = (const float*)d_in[5];
  const float* v    = (const float*)d_in[6];
  const float* W_ih = (const float*)d_in[7];
  const float* W_hh = (const float*)d_in[8];
  const float* b_ih = (const float*)d_in[9];
  const float* b_hh = (const float*)d_in[10];
  const float* Wout = (const float*)d_in[11];
  const float* bout = (const float*)d_in[12];

  float* logits = (float*)d_out;
  float* out_h  = logits + (size_t)B_ * V_;

  float* ws     = (float*)d_ws;
  __bf16* wt_hi = (__bf16*)ws;                      // H*H bf16
  __bf16* wt_lo = wt_hi + (size_t)H_ * H_;          // H*H bf16
  float* xU    = ws + 65536;                        // after 256 KB
  float* xWih  = xU + B_ * H_;
  float* ctxp  = xWih + B_ * H_;                    // NCHK*B*H
  float* mlout = ctxp + (size_t)NCHK * B_ * H_;     // NCHK*B*2
  __bf16* hn   = (__bf16*)(mlout + NCHK * B_ * 2);  // B*H bf16

  prep_k<<<dim3(B_), dim3(256), 0, stream>>>(inp, emb, U, W_ih, b_ih, b_hh, xU, xWih);
  prep_w<<<dim3(H_ * H_ / 256), dim3(256), 0, stream>>>(W, wt_hi, wt_lo);
  attn_fused<<<dim3(NCHK, B_), dim3(256), 0, stream>>>(enc, wt_hi, wt_lo, xU, v, ctxp, mlout);
  combine_hnew<<<dim3(B_), dim3(256), 0, stream>>>(ctxp, mlout, xWih, W_hh, out_h, hn);
  logits_mfma<<<dim3((V_ + 63) / 64), dim3(256), 0, stream>>>(Wout, bout, hn, logits);
}

// Round 7
// 109.579 us; speedup vs baseline: 4.7726x; 1.2189x over previous
//
#include <hip/hip_runtime.h>
#include <hip/hip_bf16.h>
#include <math.h>

#define V_ 50000
#define E_ 256
#define H_ 256
#define B_ 64
#define S_ 2048
#define NCHK 32            // S/64 score chunks (global)

typedef __attribute__((ext_vector_type(4))) float f32x4;
typedef __attribute__((ext_vector_type(8))) __bf16 bf16x8;

static __device__ __forceinline__ f32x4 mfma16(bf16x8 a, bf16x8 b, f32x4 c) {
  return __builtin_amdgcn_mfma_f32_16x16x32_bf16(a, b, c, 0, 0, 0);
}
static __device__ __forceinline__ float fast_tanh(float x) {
  const float e2 = __expf(2.0f * x);
  return 1.0f - 2.0f / (e2 + 1.0f);
}

// ---------------- prep: xU = x@U ; xWih = x@W_ih^T + b_ih + b_hh ----------------
__global__ __launch_bounds__(256) void prep_k(
    const int* __restrict__ inp, const float* __restrict__ emb,
    const float* __restrict__ U, const float* __restrict__ W_ih,
    const float* __restrict__ b_ih, const float* __restrict__ b_hh,
    float* __restrict__ xU, float* __restrict__ xWih) {
  const int b = blockIdx.x, h = threadIdx.x;
  __shared__ float xs[H_];
  xs[h] = emb[(size_t)inp[b] * E_ + h];
  __syncthreads();
  float au = 0.f, aw = 0.f;
  const float* __restrict__ wir = W_ih + (size_t)h * E_;
  for (int k = 0; k < H_; k += 4) {
    const float4 x4 = *reinterpret_cast<const float4*>(&xs[k]);
    const float4 w4 = *reinterpret_cast<const float4*>(wir + k);
    aw = fmaf(x4.x, w4.x, aw); aw = fmaf(x4.y, w4.y, aw);
    aw = fmaf(x4.z, w4.z, aw); aw = fmaf(x4.w, w4.w, aw);
    au = fmaf(x4.x, U[(size_t)(k + 0) * H_ + h], au);
    au = fmaf(x4.y, U[(size_t)(k + 1) * H_ + h], au);
    au = fmaf(x4.z, U[(size_t)(k + 2) * H_ + h], au);
    au = fmaf(x4.w, U[(size_t)(k + 3) * H_ + h], au);
  }
  xU[b * H_ + h] = au;
  xWih[b * H_ + h] = aw + b_ih[h] + b_hh[h];
}

// ---------------- prep W: transposed hi/lo bf16 tables Wt[n][k] ----------------
__global__ __launch_bounds__(256) void prep_w(
    const float* __restrict__ W, __bf16* __restrict__ wt_hi, __bf16* __restrict__ wt_lo) {
  const int idx = blockIdx.x * 256 + threadIdx.x;
  const int n = idx >> 8, k = idx & 255;
  const float w = W[(size_t)k * H_ + n];
  const __bf16 h = (__bf16)w;
  wt_hi[(size_t)n * H_ + k] = h;
  wt_lo[(size_t)n * H_ + k] = (__bf16)(w - (float)h);
}

// ---------------- fused attention over 256 s-rows per block ----------------
// 512 thr (8 waves); wave w owns cols [w*32, w*32+32) for ALL 4 row-subtiles.
// A: full 256x256 bf16 tile in LDS (128 KB), slab-staged under compute.
// B: 4 dbuf'd L2 loads per wave per step feeding 64 MFMAs (latency hidden).
__global__ __launch_bounds__(512, 2) void attn_fused(
    const float* __restrict__ enc, const __bf16* __restrict__ wt_hi,
    const __bf16* __restrict__ wt_lo, const float* __restrict__ xU,
    const float* __restrict__ vv, float* __restrict__ ctxp,
    float* __restrict__ mlout) {
  const int cb4 = blockIdx.x, b = blockIdx.y;
  const int s0 = cb4 * 256;
  const int t = threadIdx.x;
  const int w = t >> 6, l = t & 63, l15 = l & 15, lg = l >> 4;

  __shared__ __bf16 Asub[4][8][64][32];   // 128 KB, slot-rotated per 64-row subtile
  __shared__ float ered[8][4][64];        // 8 KB
  __shared__ float wgt[4][64];
  __shared__ float mlL[4][2];

  // ---- staging geometry: 2 threads per row, each 16 floats of a 32-col slab ----
  const int r = t >> 1, sg = t & 1;
  const int st_s = r >> 6, rr_s = r & 63;
  const int slot0 = ((sg * 2) + (rr_s >> 1)) & 3;
  const int slot1 = ((sg * 2 + 1) + (rr_s >> 1)) & 3;
  const float* __restrict__ encR = enc + ((size_t)b * S_ + s0 + r) * H_ + sg * 16;

  // prologue: stage slab 0
  {
    const float4 f0 = *reinterpret_cast<const float4*>(encR);
    const float4 f1 = *reinterpret_cast<const float4*>(encR + 4);
    const float4 f2 = *reinterpret_cast<const float4*>(encR + 8);
    const float4 f3 = *reinterpret_cast<const float4*>(encR + 12);
    const float xa[8] = {f0.x, f0.y, f0.z, f0.w, f1.x, f1.y, f1.z, f1.w};
    const float xb[8] = {f2.x, f2.y, f2.z, f2.w, f3.x, f3.y, f3.z, f3.w};
    bf16x8 ha, hb;
#pragma unroll
    for (int j = 0; j < 8; ++j) { ha[j] = (__bf16)xa[j]; hb[j] = (__bf16)xb[j]; }
    *reinterpret_cast<bf16x8*>(&Asub[st_s][0][rr_s][slot0 * 8]) = ha;
    *reinterpret_cast<bf16x8*>(&Asub[st_s][0][rr_s][slot1 * 8]) = hb;
  }
  // B buf 0
  bf16x8 bh[2][2], bl[2][2];
#pragma unroll
  for (int cf = 0; cf < 2; ++cf) {
    const int col = w * 32 + cf * 16 + l15;
    bh[0][cf] = *reinterpret_cast<const bf16x8*>(wt_hi + (size_t)col * H_ + lg * 8);
    bl[0][cf] = *reinterpret_cast<const bf16x8*>(wt_lo + (size_t)col * H_ + lg * 8);
  }
  __syncthreads();

  f32x4 acc[4][4][2];
#pragma unroll
  for (int i = 0; i < 4; ++i)
#pragma unroll
    for (int j = 0; j < 4; ++j)
#pragma unroll
      for (int cf = 0; cf < 2; ++cf) acc[i][j][cf] = (f32x4)(0.f);

#pragma unroll
  for (int k = 0; k < 8; ++k) {
    const int cb = k & 1;
    // stage loads for slab k+1 (HBM), consumed before the barrier
    float4 f0, f1, f2, f3;
    if (k < 7) {
      f0 = *reinterpret_cast<const float4*>(encR + (k + 1) * 32);
      f1 = *reinterpret_cast<const float4*>(encR + (k + 1) * 32 + 4);
      f2 = *reinterpret_cast<const float4*>(encR + (k + 1) * 32 + 8);
      f3 = *reinterpret_cast<const float4*>(encR + (k + 1) * 32 + 12);
    }
    // B prefetch k+1 (L2), consumed after the barrier
    if (k < 7) {
#pragma unroll
      for (int cf = 0; cf < 2; ++cf) {
        const int col = w * 32 + cf * 16 + l15;
        const size_t off = (size_t)col * H_ + (k + 1) * 32 + lg * 8;
        bh[cb ^ 1][cf] = *reinterpret_cast<const bf16x8*>(wt_hi + off);
        bl[cb ^ 1][cf] = *reinterpret_cast<const bf16x8*>(wt_lo + off);
      }
    }
    // 4 row-subtiles x (4 rf x 2 cf x 2 terms) = 64 MFMA per step
#pragma unroll
    for (int st = 0; st < 4; ++st) {
      bf16x8 ah[4];
#pragma unroll
      for (int rf = 0; rf < 4; ++rf) {
        const int rr = rf * 16 + l15;
        const int slot = (lg + (rr >> 1)) & 3;
        ah[rf] = *reinterpret_cast<const bf16x8*>(&Asub[st][k][rr][slot * 8]);
      }
#pragma unroll
      for (int rf = 0; rf < 4; ++rf)
#pragma unroll
        for (int cf = 0; cf < 2; ++cf) {
          acc[st][rf][cf] = mfma16(ah[rf], bh[cb][cf], acc[st][rf][cf]);
          acc[st][rf][cf] = mfma16(ah[rf], bl[cb][cf], acc[st][rf][cf]);
        }
    }
    // convert + write slab k+1 (disjoint from slab-k reads)
    if (k < 7) {
      const float xa[8] = {f0.x, f0.y, f0.z, f0.w, f1.x, f1.y, f1.z, f1.w};
      const float xb[8] = {f2.x, f2.y, f2.z, f2.w, f3.x, f3.y, f3.z, f3.w};
      bf16x8 ha, hb;
#pragma unroll
      for (int j = 0; j < 8; ++j) { ha[j] = (__bf16)xa[j]; hb[j] = (__bf16)xb[j]; }
      *reinterpret_cast<bf16x8*>(&Asub[st_s][k + 1][rr_s][slot0 * 8]) = ha;
      *reinterpret_cast<bf16x8*>(&Asub[st_s][k + 1][rr_s][slot1 * 8]) = hb;
    }
    __syncthreads();
  }

  // ---- epilogue: tanh + v-dot + 16-lane reduce ----
  float part[4][4][4];
#pragma unroll
  for (int st = 0; st < 4; ++st)
#pragma unroll
    for (int rf = 0; rf < 4; ++rf)
#pragma unroll
      for (int reg = 0; reg < 4; ++reg) part[st][rf][reg] = 0.f;
#pragma unroll
  for (int cf = 0; cf < 2; ++cf) {
    const int col = w * 32 + cf * 16 + l15;
    const float xu = xU[b * H_ + col];
    const float vw = vv[col];
#pragma unroll
    for (int st = 0; st < 4; ++st)
#pragma unroll
      for (int rf = 0; rf < 4; ++rf)
#pragma unroll
        for (int reg = 0; reg < 4; ++reg)
          part[st][rf][reg] += fast_tanh(xu + acc[st][rf][cf][reg]) * vw;
  }
#pragma unroll
  for (int o = 1; o < 16; o <<= 1)
#pragma unroll
    for (int st = 0; st < 4; ++st)
#pragma unroll
      for (int rf = 0; rf < 4; ++rf)
#pragma unroll
        for (int reg = 0; reg < 4; ++reg)
          part[st][rf][reg] += __shfl_xor(part[st][rf][reg], o);
  if (l15 == 0) {
#pragma unroll
    for (int st = 0; st < 4; ++st)
#pragma unroll
      for (int rf = 0; rf < 4; ++rf)
#pragma unroll
        for (int reg = 0; reg < 4; ++reg)
          ered[w][st][rf * 16 + lg * 4 + reg] = part[st][rf][reg];
  }
  __syncthreads();

  // ---- softmax stats per 64-row chunk: wave st (<4) handles chunk st ----
  if (t < 256) {
    const int st = t >> 6, rr = t & 63;
    float es = 0.f;
#pragma unroll
    for (int ww = 0; ww < 8; ++ww) es += ered[ww][st][rr];
    float m = es;
#pragma unroll
    for (int o = 1; o < 64; o <<= 1) m = fmaxf(m, __shfl_xor(m, o));
    const float we = __expf(es - m);
    float lsum = we;
#pragma unroll
    for (int o = 1; o < 64; o <<= 1) lsum += __shfl_xor(lsum, o);
    wgt[st][rr] = we;
    if (rr == 0) { mlL[st][0] = m; mlL[st][1] = lsum; }
  }
  __syncthreads();

  // ---- ctx partials from LDS bf16 tile: thread covers (st, h) over 2 iters ----
#pragma unroll
  for (int it = 0; it < 2; ++it) {
    const int st = (t >> 8) + it * 2;
    const int h = t & 255;
    const int ks = h >> 5, cc = h & 31, g = cc >> 3, j = cc & 7;
    float a0 = 0.f, a1 = 0.f;
#pragma unroll 4
    for (int s = 0; s < 64; s += 2) {
      a0 = fmaf(wgt[st][s],     (float)Asub[st][ks][s][((g + (s >> 1)) & 3) * 8 + j], a0);
      a1 = fmaf(wgt[st][s + 1], (float)Asub[st][ks][s + 1][((g + ((s + 1) >> 1)) & 3) * 8 + j], a1);
    }
    ctxp[((size_t)(cb4 * 4 + st) * B_ + b) * H_ + h] = a0 + a1;
  }
  if (t < 8)
    mlout[((cb4 * 4 + (t >> 1)) * B_ + b) * 2 + (t & 1)] = mlL[t >> 1][t & 1];
}

// ---------------- flash combine + h_new GEMV ----------------
__global__ __launch_bounds__(256) void combine_hnew(
    const float* __restrict__ ctxp, const float* __restrict__ mlout,
    const float* __restrict__ xWih, const float* __restrict__ W_hh,
    float* __restrict__ out_h, __bf16* __restrict__ hn) {
  const int b = blockIdx.x, h = threadIdx.x;
  __shared__ float cs[H_];
  float M = -3.4e38f;
#pragma unroll
  for (int cc = 0; cc < NCHK; ++cc) M = fmaxf(M, mlout[(cc * B_ + b) * 2]);
  float num = 0.f, den = 0.f;
#pragma unroll
  for (int cc = 0; cc < NCHK; ++cc) {
    const float mw = __expf(mlout[(cc * B_ + b) * 2] - M);
    den = fmaf(mw, mlout[(cc * B_ + b) * 2 + 1], den);
    num = fmaf(mw, ctxp[((size_t)cc * B_ + b) * H_ + h], num);
  }
  cs[h] = num / den;
  __syncthreads();
  const float* __restrict__ wr = W_hh + (size_t)h * H_;
  float a = xWih[b * H_ + h];
  for (int k = 0; k < H_; k += 4) {
    const float4 w4 = *reinterpret_cast<const float4*>(wr + k);
    const float4 c4 = *reinterpret_cast<const float4*>(&cs[k]);
    a = fmaf(c4.x, w4.x, a); a = fmaf(c4.y, w4.y, a);
    a = fmaf(c4.z, w4.z, a); a = fmaf(c4.w, w4.w, a);
  }
  const float hv = fast_tanh(a);
  out_h[b * H_ + h] = hv;
  hn[b * H_ + h] = (__bf16)hv;
}

// ---------------- logits = h_new @ W_out^T + b_out via pure-bf16 MFMA ----------------
__global__ __launch_bounds__(256) void logits_mfma(
    const float* __restrict__ Wout, const float* __restrict__ bout,
    const __bf16* __restrict__ hn, float* __restrict__ logits) {
  const int v0 = blockIdx.x * 64;
  const int t = threadIdx.x;
  const int wv = t >> 6, l = t & 63, l15 = l & 15, lg = l >> 4;

  __shared__ __bf16 Wsub[8][64][32];   // 32 KB, slot-rotated layout

  {
    const int srow = t >> 2, sg = t & 3;
    const int wslot = (sg + (srow >> 1)) & 3;
    const int vc = (v0 + srow) < V_ ? (v0 + srow) : (V_ - 1);
    const float* __restrict__ wr = Wout + (size_t)vc * H_ + sg * 8;
#pragma unroll
    for (int ks = 0; ks < 8; ++ks) {
      const float4 f0 = *reinterpret_cast<const float4*>(wr + ks * 32);
      const float4 f1 = *reinterpret_cast<const float4*>(wr + ks * 32 + 4);
      const float xv[8] = {f0.x, f0.y, f0.z, f0.w, f1.x, f1.y, f1.z, f1.w};
      bf16x8 h8;
#pragma unroll
      for (int j = 0; j < 8; ++j) h8[j] = (__bf16)xv[j];
      *reinterpret_cast<bf16x8*>(&Wsub[ks][srow][wslot * 8]) = h8;
    }
  }
  __syncthreads();

  f32x4 acc[4];
#pragma unroll
  for (int i = 0; i < 4; ++i) acc[i] = (f32x4)(0.f);
  const int colb = wv * 16 + l15;   // batch col
#pragma unroll
  for (int k = 0; k < 8; ++k) {
    const bf16x8 bfrag = *reinterpret_cast<const bf16x8*>(hn + (size_t)colb * H_ + k * 32 + lg * 8);
    bf16x8 ah[4];
#pragma unroll
    for (int rf = 0; rf < 4; ++rf) {
      const int rr = rf * 16 + l15;
      const int slot = (lg + (rr >> 1)) & 3;
      ah[rf] = *reinterpret_cast<const bf16x8*>(&Wsub[k][rr][slot * 8]);
    }
#pragma unroll
    for (int rf = 0; rf < 4; ++rf)
      acc[rf] = mfma16(ah[rf], bfrag, acc[rf]);
  }
#pragma unroll
  for (int rf = 0; rf < 4; ++rf) {
    const int v = v0 + rf * 16 + lg * 4;
    if (v < V_) {
      const float4 bo = *reinterpret_cast<const float4*>(bout + v);
      float4 o;
      o.x = acc[rf][0] + bo.x; o.y = acc[rf][1] + bo.y;
      o.z = acc[rf][2] + bo.z; o.w = acc[rf][3] + bo.w;
      *reinterpret_cast<float4*>(logits + (size_t)colb * V_ + v) = o;
    }
  }
}

extern "C" void kernel_launch(void* const* d_in, const int* in_sizes, int n_in,
                              void* d_out, int out_size, void* d_ws, size_t ws_size,
                              hipStream_t stream) {
  const int*   inp  = (const int*)  d_in[0];
  const float* enc  = (const float*)d_in[2];
  const float* emb  = (const float*)d_in[3];
  const float* U    = (const float*)d_in[4];
  const float* W    = (const float*)d_in[5];
  const float* v    = (const float*)d_in[6];
  const float* W_ih = (const float*)d_in[7];
  const float* W_hh = (const float*)d_in[8];
  const float* b_ih = (const float*)d_in[9];
  const float* b_hh = (const float*)d_in[10];
  const float* Wout = (const float*)d_in[11];
  const float* bout = (const float*)d_in[12];

  float* logits = (float*)d_out;
  float* out_h  = logits + (size_t)B_ * V_;

  float* ws     = (float*)d_ws;
  __bf16* wt_hi = (__bf16*)ws;                      // H*H bf16
  __bf16* wt_lo = wt_hi + (size_t)H_ * H_;          // H*H bf16
  float* xU    = ws + 65536;                        // after 256 KB
  float* xWih  = xU + B_ * H_;
  float* ctxp  = xWih + B_ * H_;                    // NCHK*B*H
  float* mlout = ctxp + (size_t)NCHK * B_ * H_;     // NCHK*B*2
  __bf16* hn   = (__bf16*)(mlout + NCHK * B_ * 2);  // B*H bf16

  prep_k<<<dim3(B_), dim3(256), 0, stream>>>(inp, emb, U, W_ih, b_ih, b_hh, xU, xWih);
  prep_w<<<dim3(H_ * H_ / 256), dim3(256), 0, stream>>>(W, wt_hi, wt_lo);
  attn_fused<<<dim3(S_ / 256, B_), dim3(512), 0, stream>>>(enc, wt_hi, wt_lo, xU, v, ctxp, mlout);
  combine_hnew<<<dim3(B_), dim3(256), 0, stream>>>(ctxp, mlout, xWih, W_hh, out_h, hn);
  logits_mfma<<<dim3((V_ + 63) / 64), dim3(256), 0, stream>>>(Wout, bout, hn, logits);
}